// Round 3
// baseline (408.025 us; speedup 1.0000x reference)
//
#include <hip/hip_runtime.h>
#include <stdint.h>

// Problem constants (B=2,S=2048,H=1024,F=4096,E=8,K=2)
#define H_DIM 1024
#define F_DIM 4096
#define E_NUM 8
#define T_NUM 4096            // B*S tokens
#define NE    8192            // K * T entries
#define BM    256
#define BN    128
#define BK    64
#define MAXT  39              // sum_e ceil(n_e/256) <= 31 + 8 = 39 (tight bound)
#define PADMAX (MAXT*BM)      // 9984 padded entry rows
#define TILE_BYTES 49152      // A 256x64x2 (32KB) + B 128x64x2 (16KB)
#define LDS_BYTES  147456     // 3 rotating buffers

// meta[] layout (ints)
#define M_NT  0
#define M_PB  1
#define M_CNT 16
#define M_CUR 24
#define M_TE  32    // [MAXT]
#define M_TR  80    // [MAXT]
#define M_INTS 128

typedef float  f32x4  __attribute__((ext_vector_type(4)));
typedef short  bf16x8 __attribute__((ext_vector_type(8)));
typedef __bf16 b16v8  __attribute__((ext_vector_type(8)));
typedef unsigned short u16;
typedef u16    u16x8  __attribute__((ext_vector_type(8)));

#define FENCE() asm volatile("" ::: "memory")
#define BAR()   __builtin_amdgcn_s_barrier()

__device__ __forceinline__ float gelu_tanh(float v) {
  float u = 0.7978845608028654f * (v + 0.044715f * v * v * v);
  return v / (1.0f + __expf(-2.0f * u));
}

__device__ __forceinline__ float b2f(u16 v) {
  union { float f; unsigned u; } x; x.u = ((unsigned)v) << 16; return x.f;
}

// async global->LDS, 16B per lane; dst wave-uniform base (lane*16 implicit)
__device__ __forceinline__ void gl16(const void* g, void* l) {
  __builtin_amdgcn_global_load_lds(
      (const __attribute__((address_space(1))) unsigned int*)g,
      (__attribute__((address_space(3))) unsigned int*)l, 16, 0, 0);
}

// ---------------- prep kernels ----------------

__global__ void k_init(int* tok, float* wgt, int* meta) {
  int i = blockIdx.x * 256 + threadIdx.x;
  if (i < PADMAX) { tok[i] = 0; wgt[i] = 0.f; }
  if (i < E_NUM) { meta[M_CNT + i] = 0; meta[M_CUR + i] = 0; }
}

__global__ void k_count(const int* __restrict__ experts, int* meta) {
  int i = blockIdx.x * 256 + threadIdx.x;
  int e = experts[i];
  int lane = threadIdx.x & 63;
#pragma unroll
  for (int ee = 0; ee < E_NUM; ++ee) {
    unsigned long long bm = __ballot(e == ee);
    if (e == ee && lane == __builtin_ctzll(bm))
      atomicAdd(&meta[M_CNT + ee], __popcll(bm));
  }
}

__global__ void k_plan(int* meta) {
  if (threadIdx.x != 0 || blockIdx.x != 0) return;
  int pb = 0, idx = 0;
  for (int e = 0; e < E_NUM; ++e) {
    int c = meta[M_CNT + e];
    int nt = (c + BM - 1) / BM;
    meta[M_PB + e] = pb;
    for (int t = 0; t < nt && idx < MAXT; ++t) {
      meta[M_TE + idx] = e; meta[M_TR + idx] = pb + t * BM; ++idx;
    }
    pb += nt * BM;
  }
  meta[M_NT] = idx;
}

__global__ void k_scatter(const int* __restrict__ experts, const float* __restrict__ probs,
                          int* tok, float* wgt, int* entpos, int* meta) {
  int i = blockIdx.x * 256 + threadIdx.x;   // i = k*T + t
  int e = experts[i];
  int t = i & (T_NUM - 1);
  float p = probs[i];
  int lane = threadIdx.x & 63;
#pragma unroll
  for (int ee = 0; ee < E_NUM; ++ee) {
    unsigned long long bm = __ballot(e == ee);
    if (e == ee) {
      int leader = __builtin_ctzll(bm);
      int cnt = __popcll(bm);
      int base = 0;
      if (lane == leader) base = atomicAdd(&meta[M_CUR + ee], cnt);
      base = __shfl(base, leader);
      int rank = __popcll(bm & ((1ull << lane) - 1ull));
      int pos = meta[M_PB + ee] + base + rank;
      tok[pos] = t;
      wgt[pos] = p;
      entpos[i] = pos;
    }
  }
}

__global__ void k_cvt_x(const float* __restrict__ x, u16* __restrict__ xbf) {
  int i = blockIdx.x * 256 + threadIdx.x;
  const f32x4* xp = (const f32x4*)x;
  f32x4 a = xp[i * 2], b = xp[i * 2 + 1];
  b16v8 o;
  o[0] = (__bf16)a[0]; o[1] = (__bf16)a[1]; o[2] = (__bf16)a[2]; o[3] = (__bf16)a[3];
  o[4] = (__bf16)b[0]; o[5] = (__bf16)b[1]; o[6] = (__bf16)b[2]; o[7] = (__bf16)b[3];
  ((b16v8*)xbf)[i] = o;
}

// transpose+convert: W fp32 [E][R][C] -> Wt bf16 [E][C][R].  grid (C/64, R/64, E)
__global__ __launch_bounds__(256) void k_trans(const float* __restrict__ W, u16* __restrict__ Wt,
                                               int R, int C) {
  alignas(16) __shared__ char L[16384];
  int e = blockIdx.z;
  int r0 = blockIdx.y * 64, c0 = blockIdx.x * 64;
  const float* We = W + (size_t)e * R * C;
  u16* Wte = Wt + (size_t)e * R * C;
  int tid = threadIdx.x;
#pragma unroll
  for (int it = 0; it < 4; ++it) {
    int gi = it * 256 + tid;
    int row = gi >> 4, c4 = gi & 15;
    f32x4 v = *(const f32x4*)(We + (size_t)(r0 + row) * C + c0 + c4 * 4);
    *(f32x4*)(L + row * 256 + ((c4 ^ (row & 15)) * 16)) = v;
  }
  __syncthreads();
#pragma unroll
  for (int s = 0; s < 2; ++s) {
    int chunk = s * 256 + tid;
    int c = chunk >> 3, rb = chunk & 7;
    b16v8 o;
#pragma unroll
    for (int j = 0; j < 8; ++j) {
      int r = rb * 8 + j;
      float f = *(const float*)(L + r * 256 + (((c >> 2) ^ (r & 15)) * 16) + (c & 3) * 4);
      o[j] = (__bf16)f;
    }
    *(b16v8*)(void*)(Wte + (size_t)(c0 + c) * R + r0 + rb * 8) = o;
  }
}

// ---------------- shared GEMM phase macros ----------------
// LDS per tile: A[256 rows][128B] then B[128 rows][128B]; chunk c of row r holds
// global k-chunk c^(r&7) (16B granular XOR swizzle). Staged via global_load_lds
// (linear LDS dest, swizzle folded into per-lane global src).

#define STAGE6(kt, bb)                                                      \
  { char* Ab_ = LDS + (bb);                                                 \
    _Pragma("unroll")                                                       \
    for (int j = 0; j < 4; ++j) gl16(asrc[j] + (kt) * 64, Ab_ + adst[j]);   \
    _Pragma("unroll")                                                       \
    for (int j = 0; j < 2; ++j) gl16(bsrc[j] + (kt) * 64, Ab_ + 32768 + bdst[j]); }

#define GEMM_COMPUTE(bb)                                                    \
  { const char* Ab_ = LDS + (bb); const char* Bb_ = Ab_ + 32768;            \
    _Pragma("unroll")                                                       \
    for (int kk = 0; kk < 2; ++kk) {                                        \
      int kbyte = kk * 64 + ((lane >> 4) << 4);                             \
      bf16x8 af[4], bfr[4];                                                 \
      _Pragma("unroll")                                                     \
      for (int m = 0; m < 4; ++m) {                                         \
        int r = wr * 64 + m * 16 + (lane & 15);                             \
        af[m] = *(const bf16x8*)(Ab_ + r * 128 + (kbyte ^ ((r & 7) << 4))); \
      }                                                                     \
      _Pragma("unroll")                                                     \
      for (int n = 0; n < 4; ++n) {                                         \
        int c = wc * 64 + n * 16 + (lane & 15);                             \
        bfr[n] = *(const bf16x8*)(Bb_ + c * 128 + (kbyte ^ ((c & 7) << 4)));\
      }                                                                     \
      __builtin_amdgcn_s_setprio(1);                                        \
      _Pragma("unroll")                                                     \
      for (int m = 0; m < 4; ++m)                                           \
        _Pragma("unroll")                                                   \
        for (int n = 0; n < 4; ++n)                                         \
          acc[m][n] = __builtin_amdgcn_mfma_f32_16x16x32_bf16(af[m], bfr[n], acc[m][n], 0, 0, 0); \
      __builtin_amdgcn_s_setprio(0);                                        \
    } }

// pipelined K-loop: stage t+2 (3-buffer rotation), counted vmcnt, raw barriers
#define GEMM_KLOOP(NT)                                                      \
  STAGE6(0, 0); STAGE6(1, TILE_BYTES);                                      \
  { int bcur = 0, bnext = 2 * TILE_BYTES;                                   \
    for (int t = 0; t < (NT); ++t) {                                        \
      FENCE();                                                              \
      if (t + 2 < (NT)) { STAGE6(t + 2, bnext);                             \
        asm volatile("s_waitcnt vmcnt(12)" ::: "memory"); }                 \
      else if (t + 1 < (NT)) { asm volatile("s_waitcnt vmcnt(6)" ::: "memory"); } \
      else { asm volatile("s_waitcnt vmcnt(0)" ::: "memory"); }             \
      BAR(); FENCE();                                                       \
      GEMM_COMPUTE(bcur);                                                   \
      FENCE(); BAR();                                                       \
      bcur  = (bcur  == 2 * TILE_BYTES) ? 0 : bcur  + TILE_BYTES;           \
      bnext = (bnext == 2 * TILE_BYTES) ? 0 : bnext + TILE_BYTES;           \
    } }                                                                     \
  FENCE();

// ---------------- GEMM1: h = gelu(x[tok] @ w1t[e] + b1[e]) -> bf16 ----------------

__global__ __launch_bounds__(512, 2) void k_gemm1(
    const u16* __restrict__ xbf, const u16* __restrict__ wbuf, const float* __restrict__ b1,
    const int* __restrict__ tok, const int* __restrict__ meta, u16* __restrict__ hbuf)
{
  extern __shared__ char LDS[];
  int nt = meta[M_NT];
  int slot = blockIdx.x;
  if (slot >= nt) return;
  int e     = meta[M_TE + slot];
  int rbase = meta[M_TR + slot];
  int cbase = blockIdx.y * BN;

  int tid = threadIdx.x;
  int lane = tid & 63;
  int wid = tid >> 6;
  int wr = wid >> 1, wc = wid & 1;        // 4M x 2N waves, 64x64 each
  int cc = tid & 7, rr = tid >> 3;

  const u16* asrc[4]; int adst[4];
#pragma unroll
  for (int j = 0; j < 4; ++j) {
    int rj = j * 64 + rr;
    int t = tok[rbase + rj];
    asrc[j] = xbf + (size_t)t * H_DIM + ((cc ^ (rj & 7)) * 8);
    adst[j] = (j * 64 + wid * 8) * 128;
  }
  const u16* bsrc[2]; int bdst[2];
#pragma unroll
  for (int j = 0; j < 2; ++j) {
    int nj = j * 64 + rr;
    bsrc[j] = wbuf + ((size_t)e * F_DIM + cbase + nj) * H_DIM + ((cc ^ (nj & 7)) * 8);
    bdst[j] = (j * 64 + wid * 8) * 128;
  }

  f32x4 acc[4][4];
#pragma unroll
  for (int m = 0; m < 4; ++m)
#pragma unroll
    for (int n = 0; n < 4; ++n) acc[m][n] = (f32x4){0.f, 0.f, 0.f, 0.f};

  GEMM_KLOOP(H_DIM / BK)   // 16 K-tiles

  // epilogue: bias + gelu + bf16, per-wave LDS bounce -> coalesced 16B stores
  float bv[4];
#pragma unroll
  for (int n = 0; n < 4; ++n) bv[n] = b1[e * F_DIM + cbase + wc * 64 + n * 16 + (lane & 15)];
  char* reg = LDS + wid * 8192;
#pragma unroll
  for (int m = 0; m < 4; ++m)
#pragma unroll
    for (int n = 0; n < 4; ++n)
#pragma unroll
      for (int q = 0; q < 4; ++q) {
        float v = acc[m][n][q] + bv[n];
        v = gelu_tanh(v);
        int row4 = ((lane >> 4) << 2) + q;
        int col = n * 16 + (lane & 15);
        *(__bf16*)(reg + m * 2048 + row4 * 128 + col * 2) = (__bf16)v;
      }
#pragma unroll
  for (int q = 0; q < 8; ++q) {
    int m = q >> 1, p = q & 1;
    int byte = p * 1024 + lane * 16;
    u16x8 v = *(const u16x8*)(reg + m * 2048 + byte);
    int row  = p * 8 + (lane >> 3);
    int colb = (lane & 7) * 16;
    size_t grow = (size_t)(rbase + wr * 64 + m * 16 + row);
    size_t gcol = (size_t)(cbase + wc * 64 + (colb >> 1));
    *(u16x8*)(hbuf + grow * F_DIM + gcol) = v;
  }
}

// ---------------- GEMM2: y[z] = h @ w2t[e] (+ b2 if z==0), split-K=2, bf16 out ----------------

__global__ __launch_bounds__(512, 2) void k_gemm2(
    const u16* __restrict__ hbuf, const u16* __restrict__ wbuf, const float* __restrict__ b2,
    const int* __restrict__ meta, u16* __restrict__ ybuf)
{
  extern __shared__ char LDS[];
  int nt = meta[M_NT];
  int slot = blockIdx.x;
  if (slot >= nt) return;
  int e     = meta[M_TE + slot];
  int rbase = meta[M_TR + slot];
  int cbase = blockIdx.y * BN;          // H tiles (8)
  int kzb   = blockIdx.z * (F_DIM / 2); // split-K half

  int tid = threadIdx.x;
  int lane = tid & 63;
  int wid = tid >> 6;
  int wr = wid >> 1, wc = wid & 1;
  int cc = tid & 7, rr = tid >> 3;

  const u16* asrc[4]; int adst[4];
#pragma unroll
  for (int j = 0; j < 4; ++j) {
    int rj = j * 64 + rr;
    asrc[j] = hbuf + (size_t)(rbase + rj) * F_DIM + kzb + ((cc ^ (rj & 7)) * 8);
    adst[j] = (j * 64 + wid * 8) * 128;
  }
  const u16* bsrc[2]; int bdst[2];
#pragma unroll
  for (int j = 0; j < 2; ++j) {
    int nj = j * 64 + rr;
    bsrc[j] = wbuf + ((size_t)e * H_DIM + cbase + nj) * F_DIM + kzb + ((cc ^ (nj & 7)) * 8);
    bdst[j] = (j * 64 + wid * 8) * 128;
  }

  f32x4 acc[4][4];
#pragma unroll
  for (int m = 0; m < 4; ++m)
#pragma unroll
    for (int n = 0; n < 4; ++n) acc[m][n] = (f32x4){0.f, 0.f, 0.f, 0.f};

  GEMM_KLOOP((F_DIM / 2) / BK)   // 32 K-tiles

  // epilogue: (+b2 if z==0), bf16, per-wave LDS bounce -> coalesced stores to ybuf
  bool z0 = (blockIdx.z == 0);
  u16* yb = ybuf + (size_t)blockIdx.z * PADMAX * H_DIM;
  float bv[4];
#pragma unroll
  for (int n = 0; n < 4; ++n)
    bv[n] = z0 ? b2[e * H_DIM + cbase + wc * 64 + n * 16 + (lane & 15)] : 0.f;
  char* reg = LDS + wid * 8192;
#pragma unroll
  for (int m = 0; m < 4; ++m)
#pragma unroll
    for (int n = 0; n < 4; ++n)
#pragma unroll
      for (int q = 0; q < 4; ++q) {
        float v = acc[m][n][q] + bv[n];
        int row4 = ((lane >> 4) << 2) + q;
        int col = n * 16 + (lane & 15);
        *(__bf16*)(reg + m * 2048 + row4 * 128 + col * 2) = (__bf16)v;
      }
#pragma unroll
  for (int q = 0; q < 8; ++q) {
    int m = q >> 1, p = q & 1;
    int byte = p * 1024 + lane * 16;
    u16x8 v = *(const u16x8*)(reg + m * 2048 + byte);
    int row  = p * 8 + (lane >> 3);
    int colb = (lane & 7) * 16;
    size_t grow = (size_t)(rbase + wr * 64 + m * 16 + row);
    size_t gcol = (size_t)(cbase + wc * 64 + (colb >> 1));
    *(u16x8*)(yb + grow * H_DIM + gcol) = v;
  }
}

// ---------------- combine: out[t] = sum_k wgt[p_k] * (y0[p_k] + y1[p_k]) ----------------

__global__ __launch_bounds__(256) void k_combine(
    const u16* __restrict__ ybuf, const float* __restrict__ wgt,
    const int* __restrict__ entpos, float* __restrict__ out)
{
  int idx = blockIdx.x * 256 + threadIdx.x;   // T*H/8 threads
  int t = idx >> 7, hc = idx & 127;
  int p0 = entpos[t], p1 = entpos[T_NUM + t];
  float w0 = wgt[p0], w1 = wgt[p1];
  const u16x8* y0 = (const u16x8*)(ybuf);
  const u16x8* y1 = (const u16x8*)(ybuf + (size_t)PADMAX * H_DIM);
  u16x8 a = y0[(size_t)p0 * (H_DIM / 8) + hc];
  u16x8 b = y1[(size_t)p0 * (H_DIM / 8) + hc];
  u16x8 c = y0[(size_t)p1 * (H_DIM / 8) + hc];
  u16x8 d = y1[(size_t)p1 * (H_DIM / 8) + hc];
  f32x4 o0, o1;
#pragma unroll
  for (int j = 0; j < 4; ++j)
    o0[j] = w0 * (b2f(a[j]) + b2f(b[j])) + w1 * (b2f(c[j]) + b2f(d[j]));
#pragma unroll
  for (int j = 0; j < 4; ++j)
    o1[j] = w0 * (b2f(a[4 + j]) + b2f(b[4 + j])) + w1 * (b2f(c[4 + j]) + b2f(d[4 + j]));
  f32x4* op = (f32x4*)(out + (size_t)t * H_DIM + hc * 8);
  op[0] = o0;
  op[1] = o1;
}

// ---------------- launch ----------------

extern "C" void kernel_launch(void* const* d_in, const int* in_sizes, int n_in,
                              void* d_out, int out_size, void* d_ws, size_t ws_size,
                              hipStream_t stream)
{
  const float* x       = (const float*)d_in[0];
  const float* probs   = (const float*)d_in[1];
  const int*   experts = (const int*)d_in[2];
  const float* w1      = (const float*)d_in[3];
  const float* b1      = (const float*)d_in[4];
  const float* w2      = (const float*)d_in[5];
  const float* b2      = (const float*)d_in[6];
  float* out = (float*)d_out;

  // workspace plan (peak 198.3 MB; wbuf reused: w1t for gemm1, then w2t for gemm2)
  char* ws = (char*)d_ws;
  size_t off = 0;
  u16*   hbuf = (u16*)(ws + off);  off += (size_t)PADMAX * F_DIM * sizeof(u16);        // 81.8 MB
  u16*   xbf  = (u16*)(ws + off);  off += (size_t)T_NUM * H_DIM * sizeof(u16);          // 8.4 MB
  u16*   wbuf = (u16*)(ws + off);  off += (size_t)E_NUM * F_DIM * H_DIM * sizeof(u16);  // 67.1 MB
  u16*   ybuf = (u16*)(ws + off);  off += (size_t)2 * PADMAX * H_DIM * sizeof(u16);     // 40.9 MB
  int*   tok  = (int*)(ws + off);  off += (size_t)PADMAX * sizeof(int);
  float* wgt  = (float*)(ws + off); off += (size_t)PADMAX * sizeof(float);
  int*   entpos = (int*)(ws + off); off += (size_t)NE * sizeof(int);
  int*   meta = (int*)(ws + off);  off += M_INTS * sizeof(int);
  (void)ws_size; (void)in_sizes; (void)n_in;

  hipFuncSetAttribute(reinterpret_cast<const void*>(&k_gemm1),
                      hipFuncAttributeMaxDynamicSharedMemorySize, LDS_BYTES);
  hipFuncSetAttribute(reinterpret_cast<const void*>(&k_gemm2),
                      hipFuncAttributeMaxDynamicSharedMemorySize, LDS_BYTES);

  k_init   <<<dim3(PADMAX / 256), 256, 0, stream>>>(tok, wgt, meta);
  k_count  <<<dim3(NE / 256), 256, 0, stream>>>(experts, meta);
  k_plan   <<<1, 1, 0, stream>>>(meta);
  k_scatter<<<dim3(NE / 256), 256, 0, stream>>>(experts, probs, tok, wgt, entpos, meta);
  k_cvt_x  <<<dim3(T_NUM * H_DIM / 8 / 256), 256, 0, stream>>>(x, xbf);
  k_trans  <<<dim3(F_DIM / 64, H_DIM / 64, E_NUM), 256, 0, stream>>>(w1, wbuf, H_DIM, F_DIM);
  k_gemm1  <<<dim3(MAXT, F_DIM / BN), 512, LDS_BYTES, stream>>>(xbf, wbuf, b1, tok, meta, hbuf);
  k_trans  <<<dim3(H_DIM / 64, F_DIM / 64, E_NUM), 256, 0, stream>>>(w2, wbuf, F_DIM, H_DIM);
  k_gemm2  <<<dim3(MAXT, H_DIM / BN, 2), 512, LDS_BYTES, stream>>>(hbuf, wbuf, b2, meta, ybuf);
  k_combine<<<dim3(T_NUM * H_DIM / 8 / 256), 256, 0, stream>>>(ybuf, wgt, entpos, out);
}

// Round 4
// 363.253 us; speedup vs baseline: 1.1233x; 1.1233x over previous
//
#include <hip/hip_runtime.h>
#include <stdint.h>

// Problem constants (B=2,S=2048,H=1024,F=4096,E=8,K=2)
#define H_DIM 1024
#define F_DIM 4096
#define E_NUM 8
#define T_NUM 4096            // B*S tokens
#define NE    8192            // K * T entries
#define BM    128
#define BN    128
#define BK    64
#define MAXTILES 72           // sum_e ceil(n_e/BM) <= NE/BM + (E-1) = 71 < 72
#define PADMAX (MAXTILES*BM)  // 9216 padded entry rows
#define BUFB  32768           // one LDS buffer: A 16KB + B 16KB

// meta[] layout (ints)
#define M_NT  0
#define M_PB  1
#define M_CNT 16
#define M_CUR 24
#define M_TE  32    // [72]
#define M_TR  104   // [72]
#define M_INTS 176

typedef float  f32x4  __attribute__((ext_vector_type(4)));
typedef short  bf16x8 __attribute__((ext_vector_type(8)));
typedef __bf16 b16v8  __attribute__((ext_vector_type(8)));
typedef unsigned short u16;
typedef u16    u16x8  __attribute__((ext_vector_type(8)));

#define BAR() __builtin_amdgcn_s_barrier()

__device__ __forceinline__ float gelu_tanh(float v) {
  float u = 0.7978845608028654f * (v + 0.044715f * v * v * v);
  return v / (1.0f + __expf(-2.0f * u));
}

__device__ __forceinline__ float b2f(u16 v) {
  union { float f; unsigned u; } x; x.u = ((unsigned)v) << 16; return x.f;
}

// async global->LDS, 16B per lane; dst wave-uniform base (lane*16 implicit)
__device__ __forceinline__ void gl16(const void* g, void* l) {
  __builtin_amdgcn_global_load_lds(
      (const __attribute__((address_space(1))) unsigned int*)g,
      (__attribute__((address_space(3))) unsigned int*)l, 16, 0, 0);
}

// ---------------- prep kernels ----------------

__global__ void k_init(int* tok, float* wgt, int* meta) {
  int i = blockIdx.x * 256 + threadIdx.x;
  if (i < PADMAX) { tok[i] = 0; wgt[i] = 0.f; }   // padded rows: token 0, weight 0
  if (i < E_NUM) { meta[M_CNT + i] = 0; meta[M_CUR + i] = 0; }
}

__global__ void k_count(const int* __restrict__ experts, int* meta) {
  int i = blockIdx.x * 256 + threadIdx.x;
  int e = experts[i];
  int lane = threadIdx.x & 63;
#pragma unroll
  for (int ee = 0; ee < E_NUM; ++ee) {
    unsigned long long bm = __ballot(e == ee);
    if (e == ee && lane == __builtin_ctzll(bm))
      atomicAdd(&meta[M_CNT + ee], __popcll(bm));
  }
}

__global__ void k_plan(int* meta) {
  if (threadIdx.x != 0 || blockIdx.x != 0) return;
  int pb = 0, idx = 0;
  for (int e = 0; e < E_NUM; ++e) {
    int c = meta[M_CNT + e];
    int nt = (c + BM - 1) / BM;
    meta[M_PB + e] = pb;
    for (int t = 0; t < nt; ++t) { meta[M_TE + idx] = e; meta[M_TR + idx] = pb + t * BM; ++idx; }
    pb += nt * BM;
  }
  meta[M_NT] = idx;
}

__global__ void k_scatter(const int* __restrict__ experts, const float* __restrict__ probs,
                          int* tok, float* wgt, int* entpos, int* meta) {
  int i = blockIdx.x * 256 + threadIdx.x;   // i = k*T + t
  int e = experts[i];
  int t = i & (T_NUM - 1);
  float p = probs[i];
  int lane = threadIdx.x & 63;
#pragma unroll
  for (int ee = 0; ee < E_NUM; ++ee) {
    unsigned long long bm = __ballot(e == ee);
    if (e == ee) {
      int leader = __builtin_ctzll(bm);
      int cnt = __popcll(bm);
      int base = 0;
      if (lane == leader) base = atomicAdd(&meta[M_CUR + ee], cnt);
      base = __shfl(base, leader);
      int rank = __popcll(bm & ((1ull << lane) - 1ull));
      int pos = meta[M_PB + ee] + base + rank;
      tok[pos] = t;
      wgt[pos] = p;
      entpos[i] = pos;
    }
  }
}

__global__ void k_cvt_x(const float* __restrict__ x, u16* __restrict__ xbf) {
  int i = blockIdx.x * 256 + threadIdx.x;
  const f32x4* xp = (const f32x4*)x;
  f32x4 a = xp[i * 2], b = xp[i * 2 + 1];
  b16v8 o;
  o[0] = (__bf16)a[0]; o[1] = (__bf16)a[1]; o[2] = (__bf16)a[2]; o[3] = (__bf16)a[3];
  o[4] = (__bf16)b[0]; o[5] = (__bf16)b[1]; o[6] = (__bf16)b[2]; o[7] = (__bf16)b[3];
  ((b16v8*)xbf)[i] = o;
}

// transpose+convert: W fp32 [E][R][C] -> Wt bf16 [E][C][R].  grid (C/64, R/64, E)
__global__ __launch_bounds__(256) void k_trans(const float* __restrict__ W, u16* __restrict__ Wt,
                                               int R, int C) {
  alignas(16) __shared__ char L[16384];
  int e = blockIdx.z;
  int r0 = blockIdx.y * 64, c0 = blockIdx.x * 64;
  const float* We = W + (size_t)e * R * C;
  u16* Wte = Wt + (size_t)e * R * C;
  int tid = threadIdx.x;
#pragma unroll
  for (int it = 0; it < 4; ++it) {
    int gi = it * 256 + tid;
    int row = gi >> 4, c4 = gi & 15;
    f32x4 v = *(const f32x4*)(We + (size_t)(r0 + row) * C + c0 + c4 * 4);
    *(f32x4*)(L + row * 256 + ((c4 ^ (row & 15)) * 16)) = v;
  }
  __syncthreads();
#pragma unroll
  for (int s = 0; s < 2; ++s) {
    int chunk = s * 256 + tid;
    int c = chunk >> 3, rb = chunk & 7;
    b16v8 o;
#pragma unroll
    for (int j = 0; j < 8; ++j) {
      int r = rb * 8 + j;
      float f = *(const float*)(L + r * 256 + (((c >> 2) ^ (r & 15)) * 16) + (c & 3) * 4);
      o[j] = (__bf16)f;
    }
    *(b16v8*)(void*)(Wte + (size_t)(c0 + c) * R + r0 + rb * 8) = o;
  }
}

// ---------------- GEMM macros ----------------
// LDS buffer (per dbuf half): A[128 rows][128B] @0, B[128 rows][128B] @16384.
// Chunk c of row r holds global k-chunk c^(r&7) (16B XOR swizzle); staged via
// global_load_lds with linear LDS dest, swizzle folded into per-lane global src.

#define STAGE8(kt, bb)                                                        \
  { char* L_ = LDS + (bb);                                                    \
    _Pragma("unroll")                                                         \
    for (int j = 0; j < 4; ++j) gl16(asrc[j] + (size_t)(kt) * BK, L_ + aoff[j]); \
    _Pragma("unroll")                                                         \
    for (int j = 0; j < 4; ++j) gl16(bsrc[j] + (size_t)(kt) * BK, L_ + 16384 + aoff[j]); }

#define GEMM_COMPUTE(bb)                                                      \
  { const char* Ab_ = LDS + (bb); const char* Bb_ = LDS + (bb) + 16384;       \
    _Pragma("unroll")                                                         \
    for (int kk = 0; kk < 2; ++kk) {                                          \
      int kbyte = kk * 64 + ((lane >> 4) << 4);                               \
      bf16x8 af[4], bfr[4];                                                   \
      _Pragma("unroll")                                                       \
      for (int m = 0; m < 4; ++m) {                                           \
        int r = wr * 64 + m * 16 + (lane & 15);                               \
        af[m] = *(const bf16x8*)(Ab_ + r * 128 + (kbyte ^ ((r & 7) << 4)));   \
      }                                                                       \
      _Pragma("unroll")                                                       \
      for (int n = 0; n < 4; ++n) {                                           \
        int c = wc * 64 + n * 16 + (lane & 15);                               \
        bfr[n] = *(const bf16x8*)(Bb_ + c * 128 + (kbyte ^ ((c & 7) << 4)));  \
      }                                                                       \
      __builtin_amdgcn_s_setprio(1);                                          \
      _Pragma("unroll")                                                       \
      for (int m = 0; m < 4; ++m)                                             \
        _Pragma("unroll")                                                     \
        for (int n = 0; n < 4; ++n)                                           \
          acc[m][n] = __builtin_amdgcn_mfma_f32_16x16x32_bf16(af[m], bfr[n], acc[m][n], 0, 0, 0); \
      __builtin_amdgcn_s_setprio(0);                                          \
    } }

// minimum-2-phase dbuf: issue STAGE(t+1) BEFORE compute(t); one vmcnt(0)+barrier per K-step
#define GEMM_KLOOP(NT)                                                        \
  STAGE8(0, 0);                                                               \
  asm volatile("s_waitcnt vmcnt(0)" ::: "memory");                            \
  BAR();                                                                      \
  { int cur = 0;                                                              \
    for (int kt = 0; kt < (NT); ++kt) {                                       \
      if (kt + 1 < (NT)) STAGE8(kt + 1, (cur ^ 1) * BUFB);                    \
      GEMM_COMPUTE(cur * BUFB);                                               \
      asm volatile("s_waitcnt vmcnt(0)" ::: "memory");                        \
      BAR();                                                                  \
      cur ^= 1;                                                               \
    } }

// ---------------- GEMM1: h = gelu(x[tok] @ w1t[e] + b1[e]) -> bf16 ----------------

__global__ __launch_bounds__(256) void k_gemm1(
    const u16* __restrict__ xbf, const u16* __restrict__ w1t, const float* __restrict__ b1,
    const int* __restrict__ tok, const int* __restrict__ meta, u16* __restrict__ hbuf)
{
  extern __shared__ char LDS[];
  // XCD chunk-swizzle: nwg = 72*32 = 2304, 288/XCD; work = cb*72 + slot
  int wg = blockIdx.x;
  int work = (wg & 7) * 288 + (wg >> 3);
  int slot = work % MAXTILES;
  int cbase = (work / MAXTILES) * BN;
  int nt = meta[M_NT];
  if (slot >= nt) return;
  int e     = meta[M_TE + slot];
  int rbase = meta[M_TR + slot];

  int tid = threadIdx.x;
  int lane = tid & 63;
  int wid = tid >> 6;
  int wr = wid >> 1, wc = wid & 1;
  int ks = lane & 7, r8 = lane >> 3;

  const u16* asrc[4]; const u16* bsrc[4]; int aoff[4];
#pragma unroll
  for (int j = 0; j < 4; ++j) {
    int r = wid * 32 + j * 8 + r8;
    int t = tok[rbase + r];
    asrc[j] = xbf + (size_t)t * H_DIM + ((ks ^ (r & 7)) * 8);
    bsrc[j] = w1t + ((size_t)e * F_DIM + cbase + r) * H_DIM + ((ks ^ (r & 7)) * 8);
    aoff[j] = (wid * 32 + j * 8) * 128;
  }

  f32x4 acc[4][4];
#pragma unroll
  for (int m = 0; m < 4; ++m)
#pragma unroll
    for (int n = 0; n < 4; ++n) acc[m][n] = (f32x4){0.f, 0.f, 0.f, 0.f};

  GEMM_KLOOP(H_DIM / BK)   // 16 K-steps

  // epilogue: bias + gelu + bf16, per-wave LDS bounce -> coalesced 16B stores
  float bv[4];
#pragma unroll
  for (int n = 0; n < 4; ++n) bv[n] = b1[e * F_DIM + cbase + wc * 64 + n * 16 + (lane & 15)];
  char* reg = LDS + wid * 8192;
#pragma unroll
  for (int m = 0; m < 4; ++m)
#pragma unroll
    for (int n = 0; n < 4; ++n)
#pragma unroll
      for (int q = 0; q < 4; ++q) {
        float v = acc[m][n][q] + bv[n];
        v = gelu_tanh(v);
        int row4 = ((lane >> 4) << 2) + q;
        int col = n * 16 + (lane & 15);
        *(__bf16*)(reg + m * 2048 + row4 * 128 + col * 2) = (__bf16)v;
      }
#pragma unroll
  for (int q = 0; q < 8; ++q) {
    int m = q >> 1, p = q & 1;
    int byte = p * 1024 + lane * 16;
    u16x8 v = *(const u16x8*)(reg + m * 2048 + byte);
    int row  = p * 8 + (lane >> 3);
    int colb = (lane & 7) * 16;
    size_t grow = (size_t)(rbase + wr * 64 + m * 16 + row);
    size_t gcol = (size_t)(cbase + wc * 64 + (colb >> 1));
    *(u16x8*)(hbuf + grow * F_DIM + gcol) = v;
  }
}

// ---------------- GEMM2: y[z] = h @ w2t[e] (+ b2 if z==0), split-K=2, bf16 out ----------------

__global__ __launch_bounds__(256) void k_gemm2(
    const u16* __restrict__ hbuf, const u16* __restrict__ w2t, const float* __restrict__ b2,
    const int* __restrict__ meta, u16* __restrict__ ybuf)
{
  extern __shared__ char LDS[];
  // nwg = 72*8*2 = 1152, 144/XCD; work = z*576 + cb*72 + slot
  int wg = blockIdx.x;
  int work = (wg & 7) * 144 + (wg >> 3);
  int zi   = work / 576;
  int rem  = work % 576;
  int slot = rem % MAXTILES;
  int cbase = (rem / MAXTILES) * BN;
  int kzb   = zi * (F_DIM / 2);
  int nt = meta[M_NT];
  if (slot >= nt) return;
  int e     = meta[M_TE + slot];
  int rbase = meta[M_TR + slot];

  int tid = threadIdx.x;
  int lane = tid & 63;
  int wid = tid >> 6;
  int wr = wid >> 1, wc = wid & 1;
  int ks = lane & 7, r8 = lane >> 3;

  const u16* asrc[4]; const u16* bsrc[4]; int aoff[4];
#pragma unroll
  for (int j = 0; j < 4; ++j) {
    int r = wid * 32 + j * 8 + r8;
    asrc[j] = hbuf + (size_t)(rbase + r) * F_DIM + kzb + ((ks ^ (r & 7)) * 8);
    bsrc[j] = w2t + ((size_t)e * H_DIM + cbase + r) * F_DIM + kzb + ((ks ^ (r & 7)) * 8);
    aoff[j] = (wid * 32 + j * 8) * 128;
  }

  f32x4 acc[4][4];
#pragma unroll
  for (int m = 0; m < 4; ++m)
#pragma unroll
    for (int n = 0; n < 4; ++n) acc[m][n] = (f32x4){0.f, 0.f, 0.f, 0.f};

  GEMM_KLOOP((F_DIM / 2) / BK)   // 32 K-steps

  // epilogue: (+b2 if z==0), bf16, per-wave LDS bounce -> coalesced stores to ybuf
  bool z0 = (zi == 0);
  u16* yb = ybuf + (size_t)zi * PADMAX * H_DIM;
  float bv[4];
#pragma unroll
  for (int n = 0; n < 4; ++n)
    bv[n] = z0 ? b2[e * H_DIM + cbase + wc * 64 + n * 16 + (lane & 15)] : 0.f;
  char* reg = LDS + wid * 8192;
#pragma unroll
  for (int m = 0; m < 4; ++m)
#pragma unroll
    for (int n = 0; n < 4; ++n)
#pragma unroll
      for (int q = 0; q < 4; ++q) {
        float v = acc[m][n][q] + bv[n];
        int row4 = ((lane >> 4) << 2) + q;
        int col = n * 16 + (lane & 15);
        *(__bf16*)(reg + m * 2048 + row4 * 128 + col * 2) = (__bf16)v;
      }
#pragma unroll
  for (int q = 0; q < 8; ++q) {
    int m = q >> 1, p = q & 1;
    int byte = p * 1024 + lane * 16;
    u16x8 v = *(const u16x8*)(reg + m * 2048 + byte);
    int row  = p * 8 + (lane >> 3);
    int colb = (lane & 7) * 16;
    size_t grow = (size_t)(rbase + wr * 64 + m * 16 + row);
    size_t gcol = (size_t)(cbase + wc * 64 + (colb >> 1));
    *(u16x8*)(yb + grow * H_DIM + gcol) = v;
  }
}

// ---------------- combine: out[t] = sum_k wgt[p_k] * (y0[p_k] + y1[p_k]) ----------------

__global__ __launch_bounds__(256) void k_combine(
    const u16* __restrict__ ybuf, const float* __restrict__ wgt,
    const int* __restrict__ entpos, float* __restrict__ out)
{
  int idx = blockIdx.x * 256 + threadIdx.x;   // T*H/8 threads
  int t = idx >> 7, hc = idx & 127;
  int p0 = entpos[t], p1 = entpos[T_NUM + t];
  float w0 = wgt[p0], w1 = wgt[p1];
  const u16x8* y0 = (const u16x8*)(ybuf);
  const u16x8* y1 = (const u16x8*)(ybuf + (size_t)PADMAX * H_DIM);
  u16x8 a = y0[(size_t)p0 * (H_DIM / 8) + hc];
  u16x8 b = y1[(size_t)p0 * (H_DIM / 8) + hc];
  u16x8 c = y0[(size_t)p1 * (H_DIM / 8) + hc];
  u16x8 d = y1[(size_t)p1 * (H_DIM / 8) + hc];
  f32x4 o0, o1;
#pragma unroll
  for (int j = 0; j < 4; ++j)
    o0[j] = w0 * (b2f(a[j]) + b2f(b[j])) + w1 * (b2f(c[j]) + b2f(d[j]));
#pragma unroll
  for (int j = 0; j < 4; ++j)
    o1[j] = w0 * (b2f(a[4 + j]) + b2f(b[4 + j])) + w1 * (b2f(c[4 + j]) + b2f(d[4 + j]));
  f32x4* op = (f32x4*)(out + (size_t)t * H_DIM + hc * 8);
  op[0] = o0;
  op[1] = o1;
}

// ---------------- launch ----------------

extern "C" void kernel_launch(void* const* d_in, const int* in_sizes, int n_in,
                              void* d_out, int out_size, void* d_ws, size_t ws_size,
                              hipStream_t stream)
{
  const float* x       = (const float*)d_in[0];
  const float* probs   = (const float*)d_in[1];
  const int*   experts = (const int*)d_in[2];
  const float* w1      = (const float*)d_in[3];
  const float* b1      = (const float*)d_in[4];
  const float* w2      = (const float*)d_in[5];
  const float* b2      = (const float*)d_in[6];
  float* out = (float*)d_out;

  char* ws = (char*)d_ws;
  size_t off = 0;
  u16*   hbuf = (u16*)(ws + off);  off += (size_t)PADMAX * F_DIM * sizeof(u16);        // 75.5 MB
  u16*   xbf  = (u16*)(ws + off);  off += (size_t)T_NUM * H_DIM * sizeof(u16);          // 8.4 MB
  u16*   w1t  = (u16*)(ws + off);  off += (size_t)E_NUM * F_DIM * H_DIM * sizeof(u16);  // 67.1 MB
  u16*   w2t  = (u16*)(ws + off);  off += (size_t)E_NUM * F_DIM * H_DIM * sizeof(u16);  // 67.1 MB
  int*   tok  = (int*)(ws + off);  off += (size_t)PADMAX * sizeof(int);
  float* wgt  = (float*)(ws + off); off += (size_t)PADMAX * sizeof(float);
  int*   entpos = (int*)(ws + off); off += (size_t)NE * sizeof(int);
  int*   meta = (int*)(ws + off);  off += M_INTS * sizeof(int);
  u16*   ybuf = w1t;   // alias: w1t dead after k_gemm1; ybuf = [2][PADMAX][H] bf16 (37.7 MB)
  (void)ws_size; (void)in_sizes; (void)n_in;

  hipFuncSetAttribute(reinterpret_cast<const void*>(&k_gemm1),
                      hipFuncAttributeMaxDynamicSharedMemorySize, 2 * BUFB);
  hipFuncSetAttribute(reinterpret_cast<const void*>(&k_gemm2),
                      hipFuncAttributeMaxDynamicSharedMemorySize, 2 * BUFB);

  k_init   <<<dim3((PADMAX + 255) / 256), 256, 0, stream>>>(tok, wgt, meta);
  k_count  <<<dim3(NE / 256), 256, 0, stream>>>(experts, meta);
  k_plan   <<<1, 1, 0, stream>>>(meta);
  k_scatter<<<dim3(NE / 256), 256, 0, stream>>>(experts, probs, tok, wgt, entpos, meta);
  k_cvt_x  <<<dim3(T_NUM * H_DIM / 8 / 256), 256, 0, stream>>>(x, xbf);
  k_trans  <<<dim3(F_DIM / 64, H_DIM / 64, E_NUM), 256, 0, stream>>>(w1, w1t, H_DIM, F_DIM);
  k_trans  <<<dim3(H_DIM / 64, F_DIM / 64, E_NUM), 256, 0, stream>>>(w2, w2t, F_DIM, H_DIM);
  k_gemm1  <<<dim3(MAXTILES * (F_DIM / BN)), 256, 2 * BUFB, stream>>>(xbf, w1t, b1, tok, meta, hbuf);
  k_gemm2  <<<dim3(MAXTILES * (H_DIM / BN) * 2), 256, 2 * BUFB, stream>>>(hbuf, w2t, b2, meta, ybuf);
  k_combine<<<dim3(T_NUM * H_DIM / 8 / 256), 256, 0, stream>>>(ybuf, wgt, entpos, out);
}

// Round 5
// 356.649 us; speedup vs baseline: 1.1441x; 1.0185x over previous
//
#include <hip/hip_runtime.h>
#include <stdint.h>

// Problem constants (B=2,S=2048,H=1024,F=4096,E=8,K=2)
#define H_DIM 1024
#define F_DIM 4096
#define E_NUM 8
#define T_NUM 4096            // B*S tokens
#define NE    8192            // K * T entries
#define BM    256
#define BN    128
#define BK    64
#define MAXT  39              // max sum_e ceil(n_e/256) = 39 (7x ceil(1/256) + ceil(8185/256))
#define PADM  (MAXT*BM)       // 9984 padded entry rows
#define TBY   49152           // ring slot: A 256x64 bf16 (32KB) @0, B 128x64 bf16 (16KB) @32768
#define LDSSZ (3*TBY)         // 144 KB

// meta[] layout (ints)
#define M_NT  0
#define M_PB  1
#define M_CNT 16
#define M_CUR 24
#define M_TE  32    // [39]
#define M_TR  72    // [39]
#define M_INTS 112

typedef float  f32x4  __attribute__((ext_vector_type(4)));
typedef short  bf16x8 __attribute__((ext_vector_type(8)));
typedef __bf16 b16v8  __attribute__((ext_vector_type(8)));
typedef unsigned short u16;
typedef u16    u16x8  __attribute__((ext_vector_type(8)));

#define BAR() __builtin_amdgcn_s_barrier()

__device__ __forceinline__ float gelu_tanh(float v) {
  float u = 0.7978845608028654f * (v + 0.044715f * v * v * v);
  return v / (1.0f + __expf(-2.0f * u));
}

__device__ __forceinline__ float b2f(u16 v) {
  union { float f; unsigned u; } x; x.u = ((unsigned)v) << 16; return x.f;
}

// async global->LDS, 16B per lane; dst wave-uniform base (lane*16 implicit)
__device__ __forceinline__ void gl16(const void* g, void* l) {
  __builtin_amdgcn_global_load_lds(
      (const __attribute__((address_space(1))) unsigned int*)g,
      (__attribute__((address_space(3))) unsigned int*)l, 16, 0, 0);
}

// ---------------- prep kernels ----------------

__global__ void k_init(int* tok, float* wgt, int* meta) {
  int i = blockIdx.x * 256 + threadIdx.x;
  if (i < PADM) { tok[i] = 0; wgt[i] = 0.f; }   // padded rows: token 0, weight 0
  if (i < E_NUM) { meta[M_CNT + i] = 0; meta[M_CUR + i] = 0; }
}

__global__ void k_count(const int* __restrict__ experts, int* meta) {
  int i = blockIdx.x * 256 + threadIdx.x;
  int e = experts[i];
  int lane = threadIdx.x & 63;
#pragma unroll
  for (int ee = 0; ee < E_NUM; ++ee) {
    unsigned long long bm = __ballot(e == ee);
    if (e == ee && lane == __builtin_ctzll(bm))
      atomicAdd(&meta[M_CNT + ee], __popcll(bm));
  }
}

__global__ void k_plan(int* meta) {
  if (threadIdx.x != 0 || blockIdx.x != 0) return;
  int pb = 0, idx = 0;
  for (int e = 0; e < E_NUM; ++e) {
    int c = meta[M_CNT + e];
    int nt = (c + BM - 1) / BM;
    meta[M_PB + e] = pb;
    for (int t = 0; t < nt && idx < MAXT; ++t) {
      meta[M_TE + idx] = e; meta[M_TR + idx] = pb + t * BM; ++idx;
    }
    pb += nt * BM;
  }
  meta[M_NT] = idx;
}

__global__ void k_scatter(const int* __restrict__ experts, const float* __restrict__ probs,
                          int* tok, float* wgt, int* entpos, int* meta) {
  int i = blockIdx.x * 256 + threadIdx.x;   // i = k*T + t
  int e = experts[i];
  int t = i & (T_NUM - 1);
  float p = probs[i];
  int lane = threadIdx.x & 63;
#pragma unroll
  for (int ee = 0; ee < E_NUM; ++ee) {
    unsigned long long bm = __ballot(e == ee);
    if (e == ee) {
      int leader = __builtin_ctzll(bm);
      int cnt = __popcll(bm);
      int base = 0;
      if (lane == leader) base = atomicAdd(&meta[M_CUR + ee], cnt);
      base = __shfl(base, leader);
      int rank = __popcll(bm & ((1ull << lane) - 1ull));
      int pos = meta[M_PB + ee] + base + rank;
      tok[pos] = t;
      wgt[pos] = p;
      entpos[i] = pos;
    }
  }
}

__global__ void k_cvt_x(const float* __restrict__ x, u16* __restrict__ xbf) {
  int i = blockIdx.x * 256 + threadIdx.x;
  const f32x4* xp = (const f32x4*)x;
  f32x4 a = xp[i * 2], b = xp[i * 2 + 1];
  b16v8 o;
  o[0] = (__bf16)a[0]; o[1] = (__bf16)a[1]; o[2] = (__bf16)a[2]; o[3] = (__bf16)a[3];
  o[4] = (__bf16)b[0]; o[5] = (__bf16)b[1]; o[6] = (__bf16)b[2]; o[7] = (__bf16)b[3];
  ((b16v8*)xbf)[i] = o;
}

// transpose+convert: W fp32 [E][R][C] -> Wt bf16 [E][C][R].  grid (C/64, R/64, E)
__global__ __launch_bounds__(256) void k_trans(const float* __restrict__ W, u16* __restrict__ Wt,
                                               int R, int C) {
  alignas(16) __shared__ char L[16384];
  int e = blockIdx.z;
  int r0 = blockIdx.y * 64, c0 = blockIdx.x * 64;
  const float* We = W + (size_t)e * R * C;
  u16* Wte = Wt + (size_t)e * R * C;
  int tid = threadIdx.x;
#pragma unroll
  for (int it = 0; it < 4; ++it) {
    int gi = it * 256 + tid;
    int row = gi >> 4, c4 = gi & 15;
    f32x4 v = *(const f32x4*)(We + (size_t)(r0 + row) * C + c0 + c4 * 4);
    *(f32x4*)(L + row * 256 + ((c4 ^ (row & 15)) * 16)) = v;
  }
  __syncthreads();
#pragma unroll
  for (int s = 0; s < 2; ++s) {
    int chunk = s * 256 + tid;
    int c = chunk >> 3, rb = chunk & 7;
    b16v8 o;
#pragma unroll
    for (int j = 0; j < 8; ++j) {
      int r = rb * 8 + j;
      float f = *(const float*)(L + r * 256 + (((c >> 2) ^ (r & 15)) * 16) + (c & 3) * 4);
      o[j] = (__bf16)f;
    }
    *(b16v8*)(void*)(Wte + (size_t)(c0 + c) * R + r0 + rb * 8) = o;
  }
}

// ---------------- GEMM: 256x128 tile, ring-3 LDS, depth-2 prefetch, counted vmcnt ----------------
// LDS slot: A[256 rows][128B] @0, B[128 rows][128B] @32768. Chunk c of row r holds
// global k-chunk c^(r&7) (16B XOR swizzle); staged via global_load_lds (linear LDS
// dest, swizzle folded into per-lane global src).
// Stage rounds: 512 thr x 16B = 8KB each; A = rounds 0..3 (rows 64j..64j+63), B = rounds 0..1.

#define STG_A(kt, sbase, j) gl16(asrc[j] + (size_t)(kt) * BK, LDS + (sbase) + (j) * 8192 + wid * 1024)
#define STG_B(kt, sbase, j) gl16(bsrc[j] + (size_t)(kt) * BK, LDS + (sbase) + 32768 + (j) * 8192 + wid * 1024)

#define STAGEALL(kt, sbase)                                                   \
  { _Pragma("unroll") for (int j = 0; j < 4; ++j) STG_A(kt, sbase, j);        \
    _Pragma("unroll") for (int j = 0; j < 2; ++j) STG_B(kt, sbase, j); }

// one phase: 8 ds_read_b128 || 3 stage rounds -> barrier -> 16 MFMA
#define PHASE(sbase, kk, STAGES)                                              \
  { asm volatile("" ::: "memory");                                           \
    const char* Ab_ = LDS + (sbase);                                         \
    const char* Bb_ = LDS + (sbase) + 32768;                                 \
    int kbyte = (kk) * 64 + ((lane >> 4) << 4);                              \
    bf16x8 af[4], bfr[4];                                                    \
    _Pragma("unroll") for (int m = 0; m < 4; ++m) {                          \
      int r = wr * 64 + m * 16 + (lane & 15);                                \
      af[m] = *(const bf16x8*)(Ab_ + r * 128 + (kbyte ^ ((r & 7) << 4)));    \
    }                                                                        \
    _Pragma("unroll") for (int n = 0; n < 4; ++n) {                          \
      int c = wc * 64 + n * 16 + (lane & 15);                                \
      bfr[n] = *(const bf16x8*)(Bb_ + c * 128 + (kbyte ^ ((c & 7) << 4)));   \
    }                                                                        \
    STAGES;                                                                  \
    asm volatile("" ::: "memory");                                           \
    BAR();                                                                   \
    __builtin_amdgcn_s_setprio(1);                                           \
    _Pragma("unroll") for (int m = 0; m < 4; ++m)                            \
      _Pragma("unroll") for (int n = 0; n < 4; ++n)                          \
        acc[m][n] = __builtin_amdgcn_mfma_f32_16x16x32_bf16(af[m], bfr[n], acc[m][n], 0, 0, 0); \
    __builtin_amdgcn_s_setprio(0);                                           \
  }

// K-loop: tile t reads slot t%3; tile t+2 staged into slot (t+2)%3 (last read at t-1,
// barrier-separated => race-free). Entry wait vmcnt(6): t's 6 loads landed (FIFO),
// t+1's 6 may stay in flight. vmcnt(0) only before the last tile.
#define GEMM_KLOOP(NT)                                                        \
  STAGEALL(0, 0)                                                              \
  STAGEALL(1, TBY)                                                            \
  { int sb = 0, s2 = 2 * TBY;                                                 \
    for (int t = 0; t < (NT); ++t) {                                          \
      if (t == (NT) - 1) { asm volatile("s_waitcnt vmcnt(0)" ::: "memory"); } \
      else               { asm volatile("s_waitcnt vmcnt(6)" ::: "memory"); } \
      BAR();                                                                  \
      bool st_ = (t + 2 < (NT));                                              \
      PHASE(sb, 0, if (st_) { STG_A(t + 2, s2, 0); STG_A(t + 2, s2, 1); STG_A(t + 2, s2, 2); }) \
      PHASE(sb, 1, if (st_) { STG_A(t + 2, s2, 3); STG_B(t + 2, s2, 0); STG_B(t + 2, s2, 1); }) \
      sb = (sb == 2 * TBY) ? 0 : sb + TBY;                                    \
      s2 = (s2 == 2 * TBY) ? 0 : s2 + TBY;                                    \
    } }                                                                       \
  BAR();

// ---------------- GEMM1: h = gelu(x[tok] @ w1t[e] + b1[e]) -> bf16 ----------------

__global__ __launch_bounds__(512, 1) void k_gemm1(
    const u16* __restrict__ xbf, const u16* __restrict__ wbuf, const float* __restrict__ b1,
    const int* __restrict__ tok, const int* __restrict__ meta, u16* __restrict__ hbuf)
{
  extern __shared__ char LDS[];
  // XCD chunk-swizzle: nwg = 39*32 = 1248 (%8==0), 156/XCD; work = cb*39 + slot
  int wg = blockIdx.x;
  int work = (wg & 7) * 156 + (wg >> 3);
  int slot = work % MAXT;
  int cbase = (work / MAXT) * BN;
  int nt = meta[M_NT];
  if (slot >= nt) return;
  int e     = meta[M_TE + slot];
  int rbase = meta[M_TR + slot];

  int tid = threadIdx.x;
  int lane = tid & 63;
  int wid = tid >> 6;
  int wr = wid >> 1, wc = wid & 1;     // 4M x 2N waves, 64x64 each
  int cc = tid & 7, rr = tid >> 3;

  const u16* asrc[4]; const u16* bsrc[2];
#pragma unroll
  for (int j = 0; j < 4; ++j) {
    int rj = j * 64 + rr;
    int t = tok[rbase + rj];
    asrc[j] = xbf + (size_t)t * H_DIM + ((cc ^ (rj & 7)) * 8);
  }
#pragma unroll
  for (int j = 0; j < 2; ++j) {
    int nj = j * 64 + rr;
    bsrc[j] = wbuf + ((size_t)e * F_DIM + cbase + nj) * H_DIM + ((cc ^ (nj & 7)) * 8);
  }

  f32x4 acc[4][4];
#pragma unroll
  for (int m = 0; m < 4; ++m)
#pragma unroll
    for (int n = 0; n < 4; ++n) acc[m][n] = (f32x4){0.f, 0.f, 0.f, 0.f};

  GEMM_KLOOP(H_DIM / BK)   // 16 K-tiles

  // epilogue: bias + gelu + bf16, per-wave LDS bounce -> coalesced 16B stores
  float bv[4];
#pragma unroll
  for (int n = 0; n < 4; ++n) bv[n] = b1[e * F_DIM + cbase + wc * 64 + n * 16 + (lane & 15)];
  char* reg = LDS + wid * 8192;
#pragma unroll
  for (int m = 0; m < 4; ++m)
#pragma unroll
    for (int n = 0; n < 4; ++n)
#pragma unroll
      for (int q = 0; q < 4; ++q) {
        float v = acc[m][n][q] + bv[n];
        v = gelu_tanh(v);
        int row4 = ((lane >> 4) << 2) + q;
        int col = n * 16 + (lane & 15);
        *(__bf16*)(reg + m * 2048 + row4 * 128 + col * 2) = (__bf16)v;
      }
#pragma unroll
  for (int q = 0; q < 8; ++q) {
    int m = q >> 1, p = q & 1;
    int byte = p * 1024 + lane * 16;
    u16x8 v = *(const u16x8*)(reg + m * 2048 + byte);
    int row  = p * 8 + (lane >> 3);
    int colb = (lane & 7) * 16;
    size_t grow = (size_t)(rbase + wr * 64 + m * 16 + row);
    size_t gcol = (size_t)(cbase + wc * 64 + (colb >> 1));
    *(u16x8*)(hbuf + grow * F_DIM + gcol) = v;
  }
}

// ---------------- GEMM2: y[z] = h @ w2t[e] (+ b2 if z==0), split-K=2, bf16 out ----------------

__global__ __launch_bounds__(512, 1) void k_gemm2(
    const u16* __restrict__ hbuf, const u16* __restrict__ wbuf, const float* __restrict__ b2,
    const int* __restrict__ meta, u16* __restrict__ ybuf)
{
  extern __shared__ char LDS[];
  // nwg = 39*8*2 = 624 (%8==0), 78/XCD; work = z*312 + cb*39 + slot
  int wg = blockIdx.x;
  int work = (wg & 7) * 78 + (wg >> 3);
  int zi   = work / 312;
  int rem  = work % 312;
  int slot = rem % MAXT;
  int cbase = (rem / MAXT) * BN;
  int kzb   = zi * (F_DIM / 2);
  int nt = meta[M_NT];
  if (slot >= nt) return;
  int e     = meta[M_TE + slot];
  int rbase = meta[M_TR + slot];

  int tid = threadIdx.x;
  int lane = tid & 63;
  int wid = tid >> 6;
  int wr = wid >> 1, wc = wid & 1;
  int cc = tid & 7, rr = tid >> 3;

  const u16* asrc[4]; const u16* bsrc[2];
#pragma unroll
  for (int j = 0; j < 4; ++j) {
    int rj = j * 64 + rr;
    asrc[j] = hbuf + (size_t)(rbase + rj) * F_DIM + kzb + ((cc ^ (rj & 7)) * 8);
  }
#pragma unroll
  for (int j = 0; j < 2; ++j) {
    int nj = j * 64 + rr;
    bsrc[j] = wbuf + ((size_t)e * H_DIM + cbase + nj) * F_DIM + kzb + ((cc ^ (nj & 7)) * 8);
  }

  f32x4 acc[4][4];
#pragma unroll
  for (int m = 0; m < 4; ++m)
#pragma unroll
    for (int n = 0; n < 4; ++n) acc[m][n] = (f32x4){0.f, 0.f, 0.f, 0.f};

  GEMM_KLOOP((F_DIM / 2) / BK)   // 32 K-tiles

  // epilogue: (+b2 if z==0), bf16, per-wave LDS bounce -> coalesced stores to ybuf
  bool z0 = (zi == 0);
  u16* yb = ybuf + (size_t)zi * PADM * H_DIM;
  float bv[4];
#pragma unroll
  for (int n = 0; n < 4; ++n)
    bv[n] = z0 ? b2[e * H_DIM + cbase + wc * 64 + n * 16 + (lane & 15)] : 0.f;
  char* reg = LDS + wid * 8192;
#pragma unroll
  for (int m = 0; m < 4; ++m)
#pragma unroll
    for (int n = 0; n < 4; ++n)
#pragma unroll
      for (int q = 0; q < 4; ++q) {
        float v = acc[m][n][q] + bv[n];
        int row4 = ((lane >> 4) << 2) + q;
        int col = n * 16 + (lane & 15);
        *(__bf16*)(reg + m * 2048 + row4 * 128 + col * 2) = (__bf16)v;
      }
#pragma unroll
  for (int q = 0; q < 8; ++q) {
    int m = q >> 1, p = q & 1;
    int byte = p * 1024 + lane * 16;
    u16x8 v = *(const u16x8*)(reg + m * 2048 + byte);
    int row  = p * 8 + (lane >> 3);
    int colb = (lane & 7) * 16;
    size_t grow = (size_t)(rbase + wr * 64 + m * 16 + row);
    size_t gcol = (size_t)(cbase + wc * 64 + (colb >> 1));
    *(u16x8*)(yb + grow * H_DIM + gcol) = v;
  }
}

// ---------------- combine: out[t] = sum_k wgt[p_k] * (y0[p_k] + y1[p_k]) ----------------

__global__ __launch_bounds__(256) void k_combine(
    const u16* __restrict__ ybuf, const float* __restrict__ wgt,
    const int* __restrict__ entpos, float* __restrict__ out)
{
  int idx = blockIdx.x * 256 + threadIdx.x;   // T*H/8 threads
  int t = idx >> 7, hc = idx & 127;
  int p0 = entpos[t], p1 = entpos[T_NUM + t];
  float w0 = wgt[p0], w1 = wgt[p1];
  const u16x8* y0 = (const u16x8*)(ybuf);
  const u16x8* y1 = (const u16x8*)(ybuf + (size_t)PADM * H_DIM);
  u16x8 a = y0[(size_t)p0 * (H_DIM / 8) + hc];
  u16x8 b = y1[(size_t)p0 * (H_DIM / 8) + hc];
  u16x8 c = y0[(size_t)p1 * (H_DIM / 8) + hc];
  u16x8 d = y1[(size_t)p1 * (H_DIM / 8) + hc];
  f32x4 o0, o1;
#pragma unroll
  for (int j = 0; j < 4; ++j)
    o0[j] = w0 * (b2f(a[j]) + b2f(b[j])) + w1 * (b2f(c[j]) + b2f(d[j]));
#pragma unroll
  for (int j = 0; j < 4; ++j)
    o1[j] = w0 * (b2f(a[4 + j]) + b2f(b[4 + j])) + w1 * (b2f(c[4 + j]) + b2f(d[4 + j]));
  f32x4* op = (f32x4*)(out + (size_t)t * H_DIM + hc * 8);
  op[0] = o0;
  op[1] = o1;
}

// ---------------- launch ----------------

extern "C" void kernel_launch(void* const* d_in, const int* in_sizes, int n_in,
                              void* d_out, int out_size, void* d_ws, size_t ws_size,
                              hipStream_t stream)
{
  const float* x       = (const float*)d_in[0];
  const float* probs   = (const float*)d_in[1];
  const int*   experts = (const int*)d_in[2];
  const float* w1      = (const float*)d_in[3];
  const float* b1      = (const float*)d_in[4];
  const float* w2      = (const float*)d_in[5];
  const float* b2      = (const float*)d_in[6];
  float* out = (float*)d_out;

  // workspace plan (~194 MB): wbuf shared by w1t (gemm1) then w2t (gemm2)
  char* ws = (char*)d_ws;
  size_t off = 0;
  u16*   hbuf = (u16*)(ws + off);  off += (size_t)PADM * F_DIM * sizeof(u16);          // 78.1 MB
  u16*   xbf  = (u16*)(ws + off);  off += (size_t)T_NUM * H_DIM * sizeof(u16);          // 8.4 MB
  u16*   wbuf = (u16*)(ws + off);  off += (size_t)E_NUM * F_DIM * H_DIM * sizeof(u16);  // 67.1 MB
  u16*   ybuf = (u16*)(ws + off);  off += (size_t)2 * PADM * H_DIM * sizeof(u16);       // 39.9 MB
  int*   tok  = (int*)(ws + off);  off += (size_t)PADM * sizeof(int);
  float* wgt  = (float*)(ws + off); off += (size_t)PADM * sizeof(float);
  int*   entpos = (int*)(ws + off); off += (size_t)NE * sizeof(int);
  int*   meta = (int*)(ws + off);  off += M_INTS * sizeof(int);
  (void)ws_size; (void)in_sizes; (void)n_in;

  hipFuncSetAttribute(reinterpret_cast<const void*>(&k_gemm1),
                      hipFuncAttributeMaxDynamicSharedMemorySize, LDSSZ);
  hipFuncSetAttribute(reinterpret_cast<const void*>(&k_gemm2),
                      hipFuncAttributeMaxDynamicSharedMemorySize, LDSSZ);

  k_init   <<<dim3(PADM / 256), 256, 0, stream>>>(tok, wgt, meta);
  k_count  <<<dim3(NE / 256), 256, 0, stream>>>(experts, meta);
  k_plan   <<<1, 1, 0, stream>>>(meta);
  k_scatter<<<dim3(NE / 256), 256, 0, stream>>>(experts, probs, tok, wgt, entpos, meta);
  k_cvt_x  <<<dim3(T_NUM * H_DIM / 8 / 256), 256, 0, stream>>>(x, xbf);
  k_trans  <<<dim3(F_DIM / 64, H_DIM / 64, E_NUM), 256, 0, stream>>>(w1, wbuf, H_DIM, F_DIM);
  k_gemm1  <<<dim3(MAXT * (F_DIM / BN)), 512, LDSSZ, stream>>>(xbf, wbuf, b1, tok, meta, hbuf);
  k_trans  <<<dim3(H_DIM / 64, F_DIM / 64, E_NUM), 256, 0, stream>>>(w2, wbuf, F_DIM, H_DIM);
  k_gemm2  <<<dim3(MAXT * (H_DIM / BN) * 2), 512, LDSSZ, stream>>>(hbuf, wbuf, b2, meta, ybuf);
  k_combine<<<dim3(T_NUM * H_DIM / 8 / 256), 256, 0, stream>>>(ybuf, wgt, entpos, out);
}

// Round 6
// 356.410 us; speedup vs baseline: 1.1448x; 1.0007x over previous
//
#include <hip/hip_runtime.h>
#include <stdint.h>

// Problem constants (B=2,S=2048,H=1024,F=4096,E=8,K=2)
#define H_DIM 1024
#define F_DIM 4096
#define E_NUM 8
#define T_NUM 4096            // B*S tokens
#define NE    8192            // K * T entries
#define BM    256
#define BN    256
#define BK    64
#define MAXT  39              // max sum_e ceil(n_e/256) = 32 + 7
#define PADM  (MAXT*BM)       // 9984 padded entry rows
#define TBY   65536           // one LDS buffer: A 256x64 bf16 (32KB) @0, B 256x64 bf16 (32KB) @32768
#define LDSSZ (2*TBY)         // 128 KB double-buffer

// meta[] layout (ints)
#define M_NT  0
#define M_PB  1
#define M_CNT 16
#define M_CUR 24
#define M_TE  32    // [39]
#define M_TR  72    // [39]
#define M_INTS 112

typedef float  f32x4  __attribute__((ext_vector_type(4)));
typedef short  bf16x8 __attribute__((ext_vector_type(8)));
typedef __bf16 b16v8  __attribute__((ext_vector_type(8)));
typedef unsigned short u16;
typedef u16    u16x8  __attribute__((ext_vector_type(8)));

#define BAR() __builtin_amdgcn_s_barrier()

__device__ __forceinline__ float gelu_tanh(float v) {
  float u = 0.7978845608028654f * (v + 0.044715f * v * v * v);
  return v / (1.0f + __expf(-2.0f * u));
}

__device__ __forceinline__ float b2f(u16 v) {
  union { float f; unsigned u; } x; x.u = ((unsigned)v) << 16; return x.f;
}

// async global->LDS, 16B per lane; dst wave-uniform base (lane*16 implicit)
__device__ __forceinline__ void gl16(const void* g, void* l) {
  __builtin_amdgcn_global_load_lds(
      (const __attribute__((address_space(1))) unsigned int*)g,
      (__attribute__((address_space(3))) unsigned int*)l, 16, 0, 0);
}

// ---------------- prep kernels ----------------

// init pads + zero counters + per-expert histogram (merged)
__global__ void k_init_count(const int* __restrict__ experts, int* tok, float* wgt, int* meta) {
  int i = blockIdx.x * 256 + threadIdx.x;   // grid covers PADM; NE < PADM
  if (i < PADM) { tok[i] = 0; wgt[i] = 0.f; }
  if (i < E_NUM) { meta[M_CNT + i] = 0; meta[M_CUR + i] = 0; }
  __syncthreads();   // counters zeroed before any atomics from this block? (cross-block: counts
                     // are zeroed by the SAME index range that writes them only in block 0; use
                     // separate pass below instead for safety)
}

__global__ void k_count(const int* __restrict__ experts, int* meta) {
  int i = blockIdx.x * 256 + threadIdx.x;   // NE threads exactly
  int e = experts[i];
  int lane = threadIdx.x & 63;
#pragma unroll
  for (int ee = 0; ee < E_NUM; ++ee) {
    unsigned long long bm = __ballot(e == ee);
    if (e == ee && lane == __builtin_ctzll(bm))
      atomicAdd(&meta[M_CNT + ee], __popcll(bm));
  }
}

__global__ void k_plan(int* meta) {
  if (threadIdx.x != 0 || blockIdx.x != 0) return;
  int pb = 0, idx = 0;
  for (int e = 0; e < E_NUM; ++e) {
    int c = meta[M_CNT + e];
    int nt = (c + BM - 1) / BM;
    meta[M_PB + e] = pb;
    for (int t = 0; t < nt && idx < MAXT; ++t) {
      meta[M_TE + idx] = e; meta[M_TR + idx] = pb + t * BM; ++idx;
    }
    pb += nt * BM;
  }
  meta[M_NT] = idx;
}

__global__ void k_scatter(const int* __restrict__ experts, const float* __restrict__ probs,
                          int* tok, float* wgt, int* entpos, int* meta) {
  int i = blockIdx.x * 256 + threadIdx.x;   // i = k*T + t
  int e = experts[i];
  int t = i & (T_NUM - 1);
  float p = probs[i];
  int lane = threadIdx.x & 63;
#pragma unroll
  for (int ee = 0; ee < E_NUM; ++ee) {
    unsigned long long bm = __ballot(e == ee);
    if (e == ee) {
      int leader = __builtin_ctzll(bm);
      int cnt = __popcll(bm);
      int base = 0;
      if (lane == leader) base = atomicAdd(&meta[M_CUR + ee], cnt);
      base = __shfl(base, leader);
      int rank = __popcll(bm & ((1ull << lane) - 1ull));
      int pos = meta[M_PB + ee] + base + rank;
      tok[pos] = t;
      wgt[pos] = p;
      entpos[i] = pos;
    }
  }
}

__global__ void k_cvt_x(const float* __restrict__ x, u16* __restrict__ xbf) {
  int i = blockIdx.x * 256 + threadIdx.x;
  const f32x4* xp = (const f32x4*)x;
  f32x4 a = xp[i * 2], b = xp[i * 2 + 1];
  b16v8 o;
  o[0] = (__bf16)a[0]; o[1] = (__bf16)a[1]; o[2] = (__bf16)a[2]; o[3] = (__bf16)a[3];
  o[4] = (__bf16)b[0]; o[5] = (__bf16)b[1]; o[6] = (__bf16)b[2]; o[7] = (__bf16)b[3];
  ((b16v8*)xbf)[i] = o;
}

// transpose+convert: W fp32 [E][R][C] -> Wt bf16 [E][C][R].  grid (C/64, R/64, E)
__global__ __launch_bounds__(256) void k_trans(const float* __restrict__ W, u16* __restrict__ Wt,
                                               int R, int C) {
  alignas(16) __shared__ char L[16384];
  int e = blockIdx.z;
  int r0 = blockIdx.y * 64, c0 = blockIdx.x * 64;
  const float* We = W + (size_t)e * R * C;
  u16* Wte = Wt + (size_t)e * R * C;
  int tid = threadIdx.x;
#pragma unroll
  for (int it = 0; it < 4; ++it) {
    int gi = it * 256 + tid;
    int row = gi >> 4, c4 = gi & 15;
    f32x4 v = *(const f32x4*)(We + (size_t)(r0 + row) * C + c0 + c4 * 4);
    *(f32x4*)(L + row * 256 + ((c4 ^ (row & 15)) * 16)) = v;
  }
  __syncthreads();
#pragma unroll
  for (int s = 0; s < 2; ++s) {
    int chunk = s * 256 + tid;
    int c = chunk >> 3, rb = chunk & 7;
    b16v8 o;
#pragma unroll
    for (int j = 0; j < 8; ++j) {
      int r = rb * 8 + j;
      float f = *(const float*)(L + r * 256 + (((c >> 2) ^ (r & 15)) * 16) + (c & 3) * 4);
      o[j] = (__bf16)f;
    }
    *(b16v8*)(void*)(Wte + (size_t)(c0 + c) * R + r0 + rb * 8) = o;
  }
}

// ---------------- GEMM: 256x256 tile, dbuf, per-wave 128x64 ----------------
// LDS buffer: A[256 rows][128B] @0, B[256 rows][128B] @32768. Chunk c of row r holds
// global k-chunk c^(r&7) (16B XOR swizzle); staged via global_load_lds (linear LDS
// dest, swizzle folded into per-lane global src). 8 stage rounds x 8KB (512thr x 16B).
// Waves: wr = wid>>2 (2 M-halves of 128 rows), wc = wid&3 (4 N-quads of 64 cols).

#define STAGEALL(kt, sb)                                                      \
  { _Pragma("unroll")                                                         \
    for (int j = 0; j < 4; ++j)                                               \
      gl16(asrc[j] + (size_t)(kt) * BK, LDS + (sb) + j * 8192 + wid * 1024);  \
    _Pragma("unroll")                                                         \
    for (int j = 0; j < 4; ++j)                                               \
      gl16(bsrc[j] + (size_t)(kt) * BK, LDS + (sb) + 32768 + j * 8192 + wid * 1024); }

#define GEMM_COMPUTE(bb)                                                      \
  { const char* Ab_ = LDS + (bb); const char* Bb_ = LDS + (bb) + 32768;       \
    _Pragma("unroll")                                                         \
    for (int kk = 0; kk < 2; ++kk) {                                          \
      int kbyte = kk * 64 + ((lane >> 4) << 4);                               \
      bf16x8 af[8], bfr[4];                                                   \
      _Pragma("unroll")                                                       \
      for (int m = 0; m < 8; ++m) {                                           \
        int r = wr * 128 + m * 16 + (lane & 15);                              \
        af[m] = *(const bf16x8*)(Ab_ + r * 128 + (kbyte ^ ((r & 7) << 4)));   \
      }                                                                       \
      _Pragma("unroll")                                                       \
      for (int n = 0; n < 4; ++n) {                                           \
        int c = wc * 64 + n * 16 + (lane & 15);                               \
        bfr[n] = *(const bf16x8*)(Bb_ + c * 128 + (kbyte ^ ((c & 7) << 4)));  \
      }                                                                       \
      __builtin_amdgcn_s_setprio(1);                                          \
      _Pragma("unroll")                                                       \
      for (int m = 0; m < 8; ++m)                                             \
        _Pragma("unroll")                                                     \
        for (int n = 0; n < 4; ++n)                                           \
          acc[m][n] = __builtin_amdgcn_mfma_f32_16x16x32_bf16(af[m], bfr[n], acc[m][n], 0, 0, 0); \
      __builtin_amdgcn_s_setprio(0);                                          \
    } }

// 2-phase dbuf: issue STAGE(t+1) BEFORE compute(t); one vmcnt(0)+barrier per K-tile.
// Stage target = buffer read at t-1, whose reads completed before the t-1 barrier.
#define GEMM_KLOOP(NT)                                                        \
  STAGEALL(0, 0);                                                             \
  asm volatile("s_waitcnt vmcnt(0)" ::: "memory");                            \
  BAR();                                                                      \
  { int cur = 0;                                                              \
    for (int kt = 0; kt < (NT); ++kt) {                                       \
      if (kt + 1 < (NT)) STAGEALL(kt + 1, (cur ^ 1) * TBY);                   \
      GEMM_COMPUTE(cur * TBY);                                                \
      asm volatile("s_waitcnt vmcnt(0)" ::: "memory");                        \
      BAR();                                                                  \
      cur ^= 1;                                                               \
    } }

// ---------------- GEMM1: h = gelu(x[tok] @ w1t[e] + b1[e]) -> bf16 ----------------

__global__ __launch_bounds__(512, 2) void k_gemm1(
    const u16* __restrict__ xbf, const u16* __restrict__ wbuf, const float* __restrict__ b1,
    const int* __restrict__ tok, const int* __restrict__ meta, u16* __restrict__ hbuf)
{
  extern __shared__ char LDS[];
  // XCD chunk-swizzle: nwg = 39*16 = 624 (%8==0), 78/XCD; work = cb*39 + slot
  int wg = blockIdx.x;
  int work = (wg & 7) * 78 + (wg >> 3);
  int slot = work % MAXT;
  int cbase = (work / MAXT) * BN;
  int nt = meta[M_NT];
  if (slot >= nt) return;
  int e     = meta[M_TE + slot];
  int rbase = meta[M_TR + slot];

  int tid = threadIdx.x;
  int lane = tid & 63;
  int wid = tid >> 6;
  int wr = wid >> 2, wc = wid & 3;     // 2M x 4N waves, 128x64 each
  int cc = tid & 7, rr = tid >> 3;

  const u16* asrc[4]; const u16* bsrc[4];
#pragma unroll
  for (int j = 0; j < 4; ++j) {
    int rj = j * 64 + rr;
    int t = tok[rbase + rj];
    asrc[j] = xbf + (size_t)t * H_DIM + ((cc ^ (rj & 7)) * 8);
    bsrc[j] = wbuf + ((size_t)e * F_DIM + cbase + rj) * H_DIM + ((cc ^ (rj & 7)) * 8);
  }

  f32x4 acc[8][4];
#pragma unroll
  for (int m = 0; m < 8; ++m)
#pragma unroll
    for (int n = 0; n < 4; ++n) acc[m][n] = (f32x4){0.f, 0.f, 0.f, 0.f};

  GEMM_KLOOP(H_DIM / BK)   // 16 K-tiles

  // epilogue: bias + gelu + bf16, per-wave LDS bounce (16KB/wave) -> coalesced 16B stores
  float bv[4];
#pragma unroll
  for (int n = 0; n < 4; ++n) bv[n] = b1[e * F_DIM + cbase + wc * 64 + n * 16 + (lane & 15)];
  char* reg = LDS + wid * 16384;
#pragma unroll
  for (int m = 0; m < 8; ++m)
#pragma unroll
    for (int n = 0; n < 4; ++n)
#pragma unroll
      for (int q = 0; q < 4; ++q) {
        float v = acc[m][n][q] + bv[n];
        v = gelu_tanh(v);
        int row4 = ((lane >> 4) << 2) + q;
        int col = n * 16 + (lane & 15);
        *(__bf16*)(reg + m * 2048 + row4 * 128 + col * 2) = (__bf16)v;
      }
#pragma unroll
  for (int q = 0; q < 16; ++q) {
    int m = q >> 1, p = q & 1;
    int byte = p * 1024 + lane * 16;
    u16x8 v = *(const u16x8*)(reg + m * 2048 + byte);
    int row  = p * 8 + (lane >> 3);
    int colb = (lane & 7) * 16;
    size_t grow = (size_t)(rbase + wr * 128 + m * 16 + row);
    size_t gcol = (size_t)(cbase + wc * 64 + (colb >> 1));
    *(u16x8*)(hbuf + grow * F_DIM + gcol) = v;
  }
}

// ---------------- GEMM2: y[z] = h @ w2t[e] (+ b2 if z==0), split-K=2, bf16 out ----------------

__global__ __launch_bounds__(512, 2) void k_gemm2(
    const u16* __restrict__ hbuf, const u16* __restrict__ wbuf, const float* __restrict__ b2,
    const int* __restrict__ meta, u16* __restrict__ ybuf)
{
  extern __shared__ char LDS[];
  // nwg = 39*4*2 = 312 (%8==0), 39/XCD; work = z*156 + cb*39 + slot
  int wg = blockIdx.x;
  int work = (wg & 7) * 39 + (wg >> 3);
  int zi   = work / 156;
  int rem  = work % 156;
  int slot = rem % MAXT;
  int cbase = (rem / MAXT) * BN;
  int kzb   = zi * (F_DIM / 2);
  int nt = meta[M_NT];
  if (slot >= nt) return;
  int e     = meta[M_TE + slot];
  int rbase = meta[M_TR + slot];

  int tid = threadIdx.x;
  int lane = tid & 63;
  int wid = tid >> 6;
  int wr = wid >> 2, wc = wid & 3;
  int cc = tid & 7, rr = tid >> 3;

  const u16* asrc[4]; const u16* bsrc[4];
#pragma unroll
  for (int j = 0; j < 4; ++j) {
    int rj = j * 64 + rr;
    asrc[j] = hbuf + (size_t)(rbase + rj) * F_DIM + kzb + ((cc ^ (rj & 7)) * 8);
    bsrc[j] = wbuf + ((size_t)e * H_DIM + cbase + rj) * F_DIM + kzb + ((cc ^ (rj & 7)) * 8);
  }

  f32x4 acc[8][4];
#pragma unroll
  for (int m = 0; m < 8; ++m)
#pragma unroll
    for (int n = 0; n < 4; ++n) acc[m][n] = (f32x4){0.f, 0.f, 0.f, 0.f};

  GEMM_KLOOP((F_DIM / 2) / BK)   // 32 K-tiles

  // epilogue: (+b2 if z==0), bf16, per-wave LDS bounce -> coalesced stores to ybuf
  bool z0 = (zi == 0);
  u16* yb = ybuf + (size_t)zi * PADM * H_DIM;
  float bv[4];
#pragma unroll
  for (int n = 0; n < 4; ++n)
    bv[n] = z0 ? b2[e * H_DIM + cbase + wc * 64 + n * 16 + (lane & 15)] : 0.f;
  char* reg = LDS + wid * 16384;
#pragma unroll
  for (int m = 0; m < 8; ++m)
#pragma unroll
    for (int n = 0; n < 4; ++n)
#pragma unroll
      for (int q = 0; q < 4; ++q) {
        float v = acc[m][n][q] + bv[n];
        int row4 = ((lane >> 4) << 2) + q;
        int col = n * 16 + (lane & 15);
        *(__bf16*)(reg + m * 2048 + row4 * 128 + col * 2) = (__bf16)v;
      }
#pragma unroll
  for (int q = 0; q < 16; ++q) {
    int m = q >> 1, p = q & 1;
    int byte = p * 1024 + lane * 16;
    u16x8 v = *(const u16x8*)(reg + m * 2048 + byte);
    int row  = p * 8 + (lane >> 3);
    int colb = (lane & 7) * 16;
    size_t grow = (size_t)(rbase + wr * 128 + m * 16 + row);
    size_t gcol = (size_t)(cbase + wc * 64 + (colb >> 1));
    *(u16x8*)(yb + grow * H_DIM + gcol) = v;
  }
}

// ---------------- combine: out[t] = sum_k wgt[p_k] * (y0[p_k] + y1[p_k]) ----------------

__global__ __launch_bounds__(256) void k_combine(
    const u16* __restrict__ ybuf, const float* __restrict__ wgt,
    const int* __restrict__ entpos, float* __restrict__ out)
{
  int idx = blockIdx.x * 256 + threadIdx.x;   // T*H/8 threads
  int t = idx >> 7, hc = idx & 127;
  int p0 = entpos[t], p1 = entpos[T_NUM + t];
  float w0 = wgt[p0], w1 = wgt[p1];
  const u16x8* y0 = (const u16x8*)(ybuf);
  const u16x8* y1 = (const u16x8*)(ybuf + (size_t)PADM * H_DIM);
  u16x8 a = y0[(size_t)p0 * (H_DIM / 8) + hc];
  u16x8 b = y1[(size_t)p0 * (H_DIM / 8) + hc];
  u16x8 c = y0[(size_t)p1 * (H_DIM / 8) + hc];
  u16x8 d = y1[(size_t)p1 * (H_DIM / 8) + hc];
  f32x4 o0, o1;
#pragma unroll
  for (int j = 0; j < 4; ++j)
    o0[j] = w0 * (b2f(a[j]) + b2f(b[j])) + w1 * (b2f(c[j]) + b2f(d[j]));
#pragma unroll
  for (int j = 0; j < 4; ++j)
    o1[j] = w0 * (b2f(a[4 + j]) + b2f(b[4 + j])) + w1 * (b2f(c[4 + j]) + b2f(d[4 + j]));
  f32x4* op = (f32x4*)(out + (size_t)t * H_DIM + hc * 8);
  op[0] = o0;
  op[1] = o1;
}

// ---------------- launch ----------------

extern "C" void kernel_launch(void* const* d_in, const int* in_sizes, int n_in,
                              void* d_out, int out_size, void* d_ws, size_t ws_size,
                              hipStream_t stream)
{
  const float* x       = (const float*)d_in[0];
  const float* probs   = (const float*)d_in[1];
  const int*   experts = (const int*)d_in[2];
  const float* w1      = (const float*)d_in[3];
  const float* b1      = (const float*)d_in[4];
  const float* w2      = (const float*)d_in[5];
  const float* b2      = (const float*)d_in[6];
  float* out = (float*)d_out;

  // workspace plan (~194 MB): wbuf shared by w1t (gemm1) then w2t (gemm2)
  char* ws = (char*)d_ws;
  size_t off = 0;
  u16*   hbuf = (u16*)(ws + off);  off += (size_t)PADM * F_DIM * sizeof(u16);          // 78.1 MB
  u16*   xbf  = (u16*)(ws + off);  off += (size_t)T_NUM * H_DIM * sizeof(u16);          // 8.4 MB
  u16*   wbuf = (u16*)(ws + off);  off += (size_t)E_NUM * F_DIM * H_DIM * sizeof(u16);  // 67.1 MB
  u16*   ybuf = (u16*)(ws + off);  off += (size_t)2 * PADM * H_DIM * sizeof(u16);       // 39.9 MB
  int*   tok  = (int*)(ws + off);  off += (size_t)PADM * sizeof(int);
  float* wgt  = (float*)(ws + off); off += (size_t)PADM * sizeof(float);
  int*   entpos = (int*)(ws + off); off += (size_t)NE * sizeof(int);
  int*   meta = (int*)(ws + off);  off += M_INTS * sizeof(int);
  (void)ws_size; (void)in_sizes; (void)n_in;

  hipFuncSetAttribute(reinterpret_cast<const void*>(&k_gemm1),
                      hipFuncAttributeMaxDynamicSharedMemorySize, LDSSZ);
  hipFuncSetAttribute(reinterpret_cast<const void*>(&k_gemm2),
                      hipFuncAttributeMaxDynamicSharedMemorySize, LDSSZ);

  k_init_count<<<dim3(PADM / 256), 256, 0, stream>>>(experts, tok, wgt, meta);
  k_count  <<<dim3(NE / 256), 256, 0, stream>>>(experts, meta);
  k_plan   <<<1, 1, 0, stream>>>(meta);
  k_scatter<<<dim3(NE / 256), 256, 0, stream>>>(experts, probs, tok, wgt, entpos, meta);
  k_cvt_x  <<<dim3(T_NUM * H_DIM / 8 / 256), 256, 0, stream>>>(x, xbf);
  k_trans  <<<dim3(F_DIM / 64, H_DIM / 64, E_NUM), 256, 0, stream>>>(w1, wbuf, H_DIM, F_DIM);
  k_gemm1  <<<dim3(MAXT * (F_DIM / BN)), 512, LDSSZ, stream>>>(xbf, wbuf, b1, tok, meta, hbuf);
  k_trans  <<<dim3(H_DIM / 64, F_DIM / 64, E_NUM), 256, 0, stream>>>(w2, wbuf, F_DIM, H_DIM);
  k_gemm2  <<<dim3(MAXT * (H_DIM / BN) * 2), 512, LDSSZ, stream>>>(hbuf, wbuf, b2, meta, ybuf);
  k_combine<<<dim3(T_NUM * H_DIM / 8 / 256), 256, 0, stream>>>(ybuf, wgt, entpos, out);
}

// Round 7
// 341.352 us; speedup vs baseline: 1.1953x; 1.0441x over previous
//
#include <hip/hip_runtime.h>
#include <stdint.h>

// Problem constants (B=2,S=2048,H=1024,F=4096,E=8,K=2)
#define H_DIM 1024
#define F_DIM 4096
#define E_NUM 8
#define T_NUM 4096            // B*S tokens
#define NE    8192            // K * T entries
#define BM    256
#define BN    256
#define BK    64
#define MAXT  40              // true bound: sum_e ceil(n_e/256) <= 39
#define PADM  9984            // 39*256 max padded rows (pb_max bound)
#define TBY   65536           // LDS buffer: A 256x64 bf16 (32KB) @0, B 256x64 bf16 (32KB) @32768
#define LDSSZ (2*TBY)         // 128 KB double-buffer

#define G1_NWG (MAXT * (F_DIM / BN))        // 640 gemm blocks in k_gemm1
#define TRW2_NWG 4096                        // fused w2-trans pair-blocks (8192 tiles / 2)

// meta[] layout (ints)
#define M_NT  0
#define M_PB  1
#define M_CNT 16
#define M_CUR 24
#define M_TE  32    // [40]
#define M_TR  72    // [40]
#define M_INTS 112

typedef float  f32x4  __attribute__((ext_vector_type(4)));
typedef short  bf16x8 __attribute__((ext_vector_type(8)));
typedef __bf16 b16v8  __attribute__((ext_vector_type(8)));
typedef unsigned short u16;
typedef u16    u16x8  __attribute__((ext_vector_type(8)));

#define BAR() __builtin_amdgcn_s_barrier()

__device__ __forceinline__ float gelu_tanh(float v) {
  float u = 0.7978845608028654f * (v + 0.044715f * v * v * v);
  return v / (1.0f + __expf(-2.0f * u));
}

__device__ __forceinline__ float b2f(u16 v) {
  union { float f; unsigned u; } x; x.u = ((unsigned)v) << 16; return x.f;
}

// async global->LDS, 16B per lane; dst wave-uniform base (lane*16 implicit)
__device__ __forceinline__ void gl16(const void* g, void* l) {
  __builtin_amdgcn_global_load_lds(
      (const __attribute__((address_space(1))) unsigned int*)g,
      (__attribute__((address_space(3))) unsigned int*)l, 16, 0, 0);
}

// 64x64 transpose+convert tile body (proven): W fp32 [E][R][C] -> Wt bf16 [E][C][R]
// operates with 256 threads (tid256) on a 16KB LDS region.
__device__ __forceinline__ void trans_tile(const float* __restrict__ W, u16* __restrict__ Wt,
                                           int R, int C, int e, int bx, int by,
                                           char* L, int tid) {
  int r0 = by * 64, c0 = bx * 64;
  const float* We = W + (size_t)e * R * C;
  u16* Wte = Wt + (size_t)e * R * C;
#pragma unroll
  for (int it = 0; it < 4; ++it) {
    int gi = it * 256 + tid;
    int row = gi >> 4, c4 = gi & 15;
    f32x4 v = *(const f32x4*)(We + (size_t)(r0 + row) * C + c0 + c4 * 4);
    *(f32x4*)(L + row * 256 + ((c4 ^ (row & 15)) * 16)) = v;
  }
  __syncthreads();
#pragma unroll
  for (int s = 0; s < 2; ++s) {
    int chunk = s * 256 + tid;
    int c = chunk >> 3, rb = chunk & 7;
    b16v8 o;
#pragma unroll
    for (int j = 0; j < 8; ++j) {
      int r = rb * 8 + j;
      float f = *(const float*)(L + r * 256 + (((c >> 2) ^ (r & 15)) * 16) + (c & 3) * 4);
      o[j] = (__bf16)f;
    }
    *(b16v8*)(void*)(Wte + (size_t)(c0 + c) * R + r0 + rb * 8) = o;
  }
}

// ---------------- prep kernels ----------------

__global__ void k_init(int* tok, float* wgt, int* meta) {
  int i = blockIdx.x * 256 + threadIdx.x;
  if (i < PADM) { tok[i] = 0; wgt[i] = 0.f; }   // padded rows: token 0, weight 0
  if (i < E_NUM) { meta[M_CNT + i] = 0; meta[M_CUR + i] = 0; }
}

__global__ void k_count(const int* __restrict__ experts, int* meta) {
  int i = blockIdx.x * 256 + threadIdx.x;   // NE threads exactly
  int e = experts[i];
  int lane = threadIdx.x & 63;
#pragma unroll
  for (int ee = 0; ee < E_NUM; ++ee) {
    unsigned long long bm = __ballot(e == ee);
    if (e == ee && lane == __builtin_ctzll(bm))
      atomicAdd(&meta[M_CNT + ee], __popcll(bm));
  }
}

__global__ void k_plan(int* meta) {
  if (threadIdx.x != 0 || blockIdx.x != 0) return;
  int pb = 0, idx = 0;
  for (int e = 0; e < E_NUM; ++e) {
    int c = meta[M_CNT + e];
    int nt = (c + BM - 1) / BM;
    meta[M_PB + e] = pb;
    for (int t = 0; t < nt && idx < MAXT; ++t) {
      meta[M_TE + idx] = e; meta[M_TR + idx] = pb + t * BM; ++idx;
    }
    pb += nt * BM;
  }
  meta[M_NT] = idx;
}

__global__ void k_scatter(const int* __restrict__ experts, const float* __restrict__ probs,
                          int* tok, float* wgt, int* entpos, int* meta) {
  int i = blockIdx.x * 256 + threadIdx.x;   // i = k*T + t
  int e = experts[i];
  int t = i & (T_NUM - 1);
  float p = probs[i];
  int lane = threadIdx.x & 63;
#pragma unroll
  for (int ee = 0; ee < E_NUM; ++ee) {
    unsigned long long bm = __ballot(e == ee);
    if (e == ee) {
      int leader = __builtin_ctzll(bm);
      int cnt = __popcll(bm);
      int base = 0;
      if (lane == leader) base = atomicAdd(&meta[M_CUR + ee], cnt);
      base = __shfl(base, leader);
      int rank = __popcll(bm & ((1ull << lane) - 1ull));
      int pos = meta[M_PB + ee] + base + rank;
      tok[pos] = t;
      wgt[pos] = p;
      entpos[i] = pos;
    }
  }
}

// fused: blocks [0, TRW1_NWG) = w1 transpose (2 tiles/block), rest = x fp32->bf16
#define TRW1_NWG 4096
__global__ __launch_bounds__(512) void k_prep(const float* __restrict__ x, u16* __restrict__ xbf,
                                              const float* __restrict__ w1, u16* __restrict__ w1t) {
  int bid = blockIdx.x;
  if (bid < TRW1_NWG) {
    // w1 [E][H=1024][F=4096] -> w1t [E][F][H]: R=1024, C=4096; 64 c-tiles x 16 r-tiles x 8 e
    alignas(16) __shared__ char L[32768];
    int ti = bid * 2 + (threadIdx.x >> 8);
    int e = ti >> 10, rem = ti & 1023;
    int bx = rem & 63, by = rem >> 6;
    trans_tile(w1, w1t, H_DIM, F_DIM, e, bx, by, L + (threadIdx.x >> 8) * 16384, threadIdx.x & 255);
    return;
  }
  int i = (bid - TRW1_NWG) * 512 + threadIdx.x;   // [0, T*H/8)
  const f32x4* xp = (const f32x4*)x;
  f32x4 a = xp[i * 2], b = xp[i * 2 + 1];
  b16v8 o;
  o[0] = (__bf16)a[0]; o[1] = (__bf16)a[1]; o[2] = (__bf16)a[2]; o[3] = (__bf16)a[3];
  o[4] = (__bf16)b[0]; o[5] = (__bf16)b[1]; o[6] = (__bf16)b[2]; o[7] = (__bf16)b[3];
  ((b16v8*)xbf)[i] = o;
}

// standalone w2 transpose (serial fallback path only). grid (C/64, R/64, E)
__global__ __launch_bounds__(256) void k_trans(const float* __restrict__ W, u16* __restrict__ Wt,
                                               int R, int C) {
  alignas(16) __shared__ char L[16384];
  trans_tile(W, Wt, R, C, blockIdx.z, blockIdx.x, blockIdx.y, L, threadIdx.x);
}

// ---------------- GEMM: 256x256 tile, dbuf, per-wave 128x64 ----------------
// LDS buffer: A[256 rows][128B] @0, B[256 rows][128B] @32768. Chunk c of row r holds
// global k-chunk c^(r&7) (16B XOR swizzle); staged via global_load_lds (linear LDS
// dest, swizzle folded into per-lane global src). 8 stage rounds x 8KB (512thr x 16B).

#define STAGEALL(kt, sb)                                                      \
  { _Pragma("unroll")                                                         \
    for (int j = 0; j < 4; ++j)                                               \
      gl16(asrc[j] + (size_t)(kt) * BK, LDS + (sb) + j * 8192 + wid * 1024);  \
    _Pragma("unroll")                                                         \
    for (int j = 0; j < 4; ++j)                                               \
      gl16(bsrc[j] + (size_t)(kt) * BK, LDS + (sb) + 32768 + j * 8192 + wid * 1024); }

#define GEMM_COMPUTE(bb)                                                      \
  { const char* Ab_ = LDS + (bb); const char* Bb_ = LDS + (bb) + 32768;       \
    _Pragma("unroll")                                                         \
    for (int kk = 0; kk < 2; ++kk) {                                          \
      int kbyte = kk * 64 + ((lane >> 4) << 4);                               \
      bf16x8 af[8], bfr[4];                                                   \
      _Pragma("unroll")                                                       \
      for (int m = 0; m < 8; ++m) {                                           \
        int r = wr * 128 + m * 16 + (lane & 15);                              \
        af[m] = *(const bf16x8*)(Ab_ + r * 128 + (kbyte ^ ((r & 7) << 4)));   \
      }                                                                       \
      _Pragma("unroll")                                                       \
      for (int n = 0; n < 4; ++n) {                                           \
        int c = wc * 64 + n * 16 + (lane & 15);                               \
        bfr[n] = *(const bf16x8*)(Bb_ + c * 128 + (kbyte ^ ((c & 7) << 4)));  \
      }                                                                       \
      __builtin_amdgcn_s_setprio(1);                                          \
      _Pragma("unroll")                                                       \
      for (int m = 0; m < 8; ++m)                                             \
        _Pragma("unroll")                                                     \
        for (int n = 0; n < 4; ++n)                                           \
          acc[m][n] = __builtin_amdgcn_mfma_f32_16x16x32_bf16(af[m], bfr[n], acc[m][n], 0, 0, 0); \
      __builtin_amdgcn_s_setprio(0);                                          \
    } }

// 2-phase dbuf: issue STAGE(t+1) BEFORE compute(t); one vmcnt(0)+barrier per K-tile.
#define GEMM_KLOOP(NT)                                                        \
  STAGEALL(0, 0);                                                             \
  asm volatile("s_waitcnt vmcnt(0)" ::: "memory");                            \
  BAR();                                                                      \
  { int cur = 0;                                                              \
    for (int kt = 0; kt < (NT); ++kt) {                                       \
      if (kt + 1 < (NT)) STAGEALL(kt + 1, (cur ^ 1) * TBY);                   \
      GEMM_COMPUTE(cur * TBY);                                                \
      asm volatile("s_waitcnt vmcnt(0)" ::: "memory");                        \
      BAR();                                                                  \
      cur ^= 1;                                                               \
    } }

// ---------------- GEMM1 (+ fused w2 transpose role blocks) ----------------

__global__ __launch_bounds__(512, 1) void k_gemm1(
    const u16* __restrict__ xbf, const u16* __restrict__ w1t, const float* __restrict__ b1,
    const int* __restrict__ tok, const int* __restrict__ meta, u16* __restrict__ hbuf,
    const float* __restrict__ w2, u16* __restrict__ w2t)
{
  extern __shared__ char LDS[];
  int wg = blockIdx.x;
  if (wg >= G1_NWG) {
    // fused role: w2 [E][F=4096][H=1024] -> w2t [E][H][F]: R=4096, C=1024; 16 c x 64 r x 8 e
    int ti = (wg - G1_NWG) * 2 + (threadIdx.x >> 8);
    int e = ti >> 10, rem = ti & 1023;
    int bx = rem & 15, by = rem >> 4;
    trans_tile(w2, w2t, F_DIM, H_DIM, e, bx, by, LDS + (threadIdx.x >> 8) * 16384, threadIdx.x & 255);
    return;
  }
  // XCD chunk-swizzle over 640 gemm blocks: 80/XCD
  int work = (wg & 7) * (G1_NWG / 8) + (wg >> 3);
  int slot = work % MAXT;
  int cbase = (work / MAXT) * BN;
  int nt = meta[M_NT];
  if (slot >= nt) return;
  int e     = meta[M_TE + slot];
  int rbase = meta[M_TR + slot];

  int tid = threadIdx.x;
  int lane = tid & 63;
  int wid = tid >> 6;
  int wr = wid >> 2, wc = wid & 3;     // 2M x 4N waves, 128x64 each
  int cc = tid & 7, rr = tid >> 3;

  const u16* asrc[4]; const u16* bsrc[4];
#pragma unroll
  for (int j = 0; j < 4; ++j) {
    int rj = j * 64 + rr;
    int t = tok[rbase + rj];
    asrc[j] = xbf + (size_t)t * H_DIM + ((cc ^ (rj & 7)) * 8);
    bsrc[j] = w1t + ((size_t)e * F_DIM + cbase + rj) * H_DIM + ((cc ^ (rj & 7)) * 8);
  }

  f32x4 acc[8][4];
#pragma unroll
  for (int m = 0; m < 8; ++m)
#pragma unroll
    for (int n = 0; n < 4; ++n) acc[m][n] = (f32x4){0.f, 0.f, 0.f, 0.f};

  GEMM_KLOOP(H_DIM / BK)   // 16 K-tiles

  // epilogue: bias + gelu + bf16, per-wave LDS bounce (16KB/wave) -> coalesced 16B stores
  float bv[4];
#pragma unroll
  for (int n = 0; n < 4; ++n) bv[n] = b1[e * F_DIM + cbase + wc * 64 + n * 16 + (lane & 15)];
  char* reg = LDS + wid * 16384;
#pragma unroll
  for (int m = 0; m < 8; ++m)
#pragma unroll
    for (int n = 0; n < 4; ++n)
#pragma unroll
      for (int q = 0; q < 4; ++q) {
        float v = acc[m][n][q] + bv[n];
        v = gelu_tanh(v);
        int row4 = ((lane >> 4) << 2) + q;
        int col = n * 16 + (lane & 15);
        *(__bf16*)(reg + m * 2048 + row4 * 128 + col * 2) = (__bf16)v;
      }
#pragma unroll
  for (int q = 0; q < 16; ++q) {
    int m = q >> 1, p = q & 1;
    int byte = p * 1024 + lane * 16;
    u16x8 v = *(const u16x8*)(reg + m * 2048 + byte);
    int row  = p * 8 + (lane >> 3);
    int colb = (lane & 7) * 16;
    size_t grow = (size_t)(rbase + wr * 128 + m * 16 + row);
    size_t gcol = (size_t)(cbase + wc * 64 + (colb >> 1));
    *(u16x8*)(hbuf + grow * F_DIM + gcol) = v;
  }
}

// ---------------- GEMM2: y[z] = h @ w2t[e] (+ b2 if z==0), split-K=2, bf16 out ----------------

__global__ __launch_bounds__(512, 1) void k_gemm2(
    const u16* __restrict__ hbuf, const u16* __restrict__ w2t, const float* __restrict__ b2,
    const int* __restrict__ meta, u16* __restrict__ ybuf)
{
  extern __shared__ char LDS[];
  // nwg = 40*4*2 = 320 (%8==0), 40/XCD
  int wg = blockIdx.x;
  int work = (wg & 7) * 40 + (wg >> 3);
  int zi   = work / 160;
  int rem  = work % 160;
  int slot = rem % MAXT;
  int cbase = (rem / MAXT) * BN;
  int kzb   = zi * (F_DIM / 2);
  int nt = meta[M_NT];
  if (slot >= nt) return;
  int e     = meta[M_TE + slot];
  int rbase = meta[M_TR + slot];

  int tid = threadIdx.x;
  int lane = tid & 63;
  int wid = tid >> 6;
  int wr = wid >> 2, wc = wid & 3;
  int cc = tid & 7, rr = tid >> 3;

  const u16* asrc[4]; const u16* bsrc[4];
#pragma unroll
  for (int j = 0; j < 4; ++j) {
    int rj = j * 64 + rr;
    asrc[j] = hbuf + (size_t)(rbase + rj) * F_DIM + kzb + ((cc ^ (rj & 7)) * 8);
    bsrc[j] = w2t + ((size_t)e * H_DIM + cbase + rj) * F_DIM + kzb + ((cc ^ (rj & 7)) * 8);
  }

  f32x4 acc[8][4];
#pragma unroll
  for (int m = 0; m < 8; ++m)
#pragma unroll
    for (int n = 0; n < 4; ++n) acc[m][n] = (f32x4){0.f, 0.f, 0.f, 0.f};

  GEMM_KLOOP((F_DIM / 2) / BK)   // 32 K-tiles

  // epilogue: (+b2 if z==0), bf16, per-wave LDS bounce -> coalesced stores to ybuf
  bool z0 = (zi == 0);
  u16* yb = ybuf + (size_t)zi * PADM * H_DIM;
  float bv[4];
#pragma unroll
  for (int n = 0; n < 4; ++n)
    bv[n] = z0 ? b2[e * H_DIM + cbase + wc * 64 + n * 16 + (lane & 15)] : 0.f;
  char* reg = LDS + wid * 16384;
#pragma unroll
  for (int m = 0; m < 8; ++m)
#pragma unroll
    for (int n = 0; n < 4; ++n)
#pragma unroll
      for (int q = 0; q < 4; ++q) {
        float v = acc[m][n][q] + bv[n];
        int row4 = ((lane >> 4) << 2) + q;
        int col = n * 16 + (lane & 15);
        *(__bf16*)(reg + m * 2048 + row4 * 128 + col * 2) = (__bf16)v;
      }
#pragma unroll
  for (int q = 0; q < 16; ++q) {
    int m = q >> 1, p = q & 1;
    int byte = p * 1024 + lane * 16;
    u16x8 v = *(const u16x8*)(reg + m * 2048 + byte);
    int row  = p * 8 + (lane >> 3);
    int colb = (lane & 7) * 16;
    size_t grow = (size_t)(rbase + wr * 128 + m * 16 + row);
    size_t gcol = (size_t)(cbase + wc * 64 + (colb >> 1));
    *(u16x8*)(yb + grow * H_DIM + gcol) = v;
  }
}

// ---------------- combine: out[t] = sum_k wgt[p_k] * (y0[p_k] + y1[p_k]) ----------------

__global__ __launch_bounds__(256) void k_combine(
    const u16* __restrict__ ybuf, const float* __restrict__ wgt,
    const int* __restrict__ entpos, float* __restrict__ out)
{
  int idx = blockIdx.x * 256 + threadIdx.x;   // T*H/8 threads
  int t = idx >> 7, hc = idx & 127;
  int p0 = entpos[t], p1 = entpos[T_NUM + t];
  float w0 = wgt[p0], w1 = wgt[p1];
  const u16x8* y0 = (const u16x8*)(ybuf);
  const u16x8* y1 = (const u16x8*)(ybuf + (size_t)PADM * H_DIM);
  u16x8 a = y0[(size_t)p0 * (H_DIM / 8) + hc];
  u16x8 b = y1[(size_t)p0 * (H_DIM / 8) + hc];
  u16x8 c = y0[(size_t)p1 * (H_DIM / 8) + hc];
  u16x8 d = y1[(size_t)p1 * (H_DIM / 8) + hc];
  f32x4 o0, o1;
#pragma unroll
  for (int j = 0; j < 4; ++j)
    o0[j] = w0 * (b2f(a[j]) + b2f(b[j])) + w1 * (b2f(c[j]) + b2f(d[j]));
#pragma unroll
  for (int j = 0; j < 4; ++j)
    o1[j] = w0 * (b2f(a[4 + j]) + b2f(b[4 + j])) + w1 * (b2f(c[4 + j]) + b2f(d[4 + j]));
  f32x4* op = (f32x4*)(out + (size_t)t * H_DIM + hc * 8);
  op[0] = o0;
  op[1] = o1;
}

// ---------------- launch ----------------

extern "C" void kernel_launch(void* const* d_in, const int* in_sizes, int n_in,
                              void* d_out, int out_size, void* d_ws, size_t ws_size,
                              hipStream_t stream)
{
  const float* x       = (const float*)d_in[0];
  const float* probs   = (const float*)d_in[1];
  const int*   experts = (const int*)d_in[2];
  const float* w1      = (const float*)d_in[3];
  const float* b1      = (const float*)d_in[4];
  const float* w2      = (const float*)d_in[5];
  const float* b2      = (const float*)d_in[6];
  float* out = (float*)d_out;

  // base workspace plan (~198.3 MB); separate w2t (+67.1 MB) only if ws permits
  char* ws = (char*)d_ws;
  size_t off = 0;
  u16*   hbuf = (u16*)(ws + off);  off += (size_t)PADM * F_DIM * sizeof(u16);          // 81.8 MB
  u16*   xbf  = (u16*)(ws + off);  off += (size_t)T_NUM * H_DIM * sizeof(u16);          // 8.4 MB
  u16*   w1t  = (u16*)(ws + off);  off += (size_t)E_NUM * F_DIM * H_DIM * sizeof(u16);  // 67.1 MB
  u16*   ybuf = (u16*)(ws + off);  off += (size_t)2 * PADM * H_DIM * sizeof(u16);       // 40.9 MB
  int*   tok  = (int*)(ws + off);  off += (size_t)PADM * sizeof(int);
  float* wgt  = (float*)(ws + off); off += (size_t)PADM * sizeof(float);
  int*   entpos = (int*)(ws + off); off += (size_t)NE * sizeof(int);
  int*   meta = (int*)(ws + off);  off += M_INTS * sizeof(int);
  size_t w2t_bytes = (size_t)E_NUM * F_DIM * H_DIM * sizeof(u16);
  bool fused = (ws_size >= off + w2t_bytes);
  u16* w2t = fused ? (u16*)(ws + off) : w1t;   // fallback: reuse w1t after gemm1
  (void)in_sizes; (void)n_in;

  hipFuncSetAttribute(reinterpret_cast<const void*>(&k_gemm1),
                      hipFuncAttributeMaxDynamicSharedMemorySize, LDSSZ);
  hipFuncSetAttribute(reinterpret_cast<const void*>(&k_gemm2),
                      hipFuncAttributeMaxDynamicSharedMemorySize, LDSSZ);

  k_init   <<<dim3((PADM + 255) / 256), 256, 0, stream>>>(tok, wgt, meta);
  k_count  <<<dim3(NE / 256), 256, 0, stream>>>(experts, meta);
  k_plan   <<<1, 1, 0, stream>>>(meta);
  k_scatter<<<dim3(NE / 256), 256, 0, stream>>>(experts, probs, tok, wgt, entpos, meta);
  k_prep   <<<dim3(TRW1_NWG + T_NUM * H_DIM / 8 / 512), 512, 0, stream>>>(x, xbf, w1, w1t);
  k_gemm1  <<<dim3(G1_NWG + (fused ? TRW2_NWG : 0)), 512, LDSSZ, stream>>>(
              xbf, w1t, b1, tok, meta, hbuf, w2, w2t);
  if (!fused)
    k_trans<<<dim3(H_DIM / 64, F_DIM / 64, E_NUM), 256, 0, stream>>>(w2, w2t, F_DIM, H_DIM);
  k_gemm2  <<<dim3(MAXT * (H_DIM / BN) * 2), 512, LDSSZ, stream>>>(hbuf, w2t, b2, meta, ybuf);
  k_combine<<<dim3(T_NUM * H_DIM / 8 / 256), 256, 0, stream>>>(ybuf, wgt, entpos, out);
}